// Round 2
// baseline (549.933 us; speedup 1.0000x reference)
//
#include <hip/hip_runtime.h>
#include <math.h>

#define SQ_EPS 1e-12f
#define BN_EPS 1e-5f

typedef short short8 __attribute__((ext_vector_type(8)));
typedef float f32x4 __attribute__((ext_vector_type(4)));
typedef unsigned short ushort_t;

__device__ inline unsigned short f2bf(float x) {
    unsigned int u = __float_as_uint(x);
    unsigned int r = (u + 0x7fffu + ((u >> 16) & 1u)) >> 16;   // round-to-nearest-even
    return (unsigned short)r;
}
__device__ inline float bf2f(unsigned short h) {
    return __uint_as_float(((unsigned int)h) << 16);
}

// ================= fused conv (3 branches, pooling inline) =================
template<int IH, int IW, int KS, int OH, int OW>
__device__ void conv_body(const float* __restrict__ w, const float* __restrict__ bias,
                          ushort_t* __restrict__ yh, ushort_t* __restrict__ yl,
                          float* __restrict__ partial,
                          int b, int tid, float* s_img, float* s_w, float* s_red) {
    constexpr int KK = KS * KS;
    constexpr int OS = OH * OW;
    for (int i = tid; i < 128 * KK; i += 256) s_w[i] = w[i];
    __syncthreads();
    int c = tid & 127, half = tid >> 7;
    float bias_c = bias[c];
    float bsum = 0.f, bsq = 0.f;
    for (int r = half; r < OH; r += 2) {
        float acc[OW];
        #pragma unroll
        for (int j = 0; j < OW; ++j) acc[j] = bias_c;
        for (int u = 0; u < KS; ++u) {
            float rg[OW + KS - 1];
            #pragma unroll
            for (int j = 0; j < OW + KS - 1; ++j) rg[j] = s_img[(r + u) * IW + j];
            #pragma unroll
            for (int v = 0; v < KS; ++v) {
                float wv = s_w[c * KK + u * KS + v];
                #pragma unroll
                for (int j = 0; j < OW; ++j) acc[j] += wv * rg[j + v];
            }
        }
        #pragma unroll
        for (int j = 0; j < OW; ++j) {
            float val = fmaxf(acc[j], 0.f);
            bsum += val; bsq += val * val;
            unsigned short h = f2bf(val);
            unsigned short lo = f2bf(val - bf2f(h));
            int oidx = ((b * OS) + r * OW + j) * 128 + c;
            yh[oidx] = h; yl[oidx] = lo;
        }
    }
    s_red[tid] = bsum; __syncthreads();
    if (tid < 128) partial[b * 256 + c] = s_red[tid] + s_red[tid + 128];
    __syncthreads();
    s_red[tid] = bsq; __syncthreads();
    if (tid < 128) partial[b * 256 + 128 + c] = s_red[tid] + s_red[tid + 128];
}

__global__ __launch_bounds__(256) void conv_all_kernel(
        const float* __restrict__ img,
        const float* __restrict__ c1w, const float* __restrict__ c1b,
        const float* __restrict__ c2w, const float* __restrict__ c2b,
        const float* __restrict__ c3w, const float* __restrict__ c3b,
        ushort_t* __restrict__ yh1, ushort_t* __restrict__ yl1,
        ushort_t* __restrict__ yh2, ushort_t* __restrict__ yl2,
        ushort_t* __restrict__ yh3, ushort_t* __restrict__ yl3,
        float* __restrict__ partial_base) {
    __shared__ float s_img[784];
    __shared__ float s_tmp[196];
    __shared__ float s_w[128 * 81];
    __shared__ float s_red[256];
    int br = blockIdx.x >> 8, b = blockIdx.x & 255, tid = threadIdx.x;
    const float* im = img + b * 784;
    for (int i = tid; i < 784; i += 256) s_img[i] = im[i];
    __syncthreads();
    if (br <= 1) {
        for (int idx = tid; idx < 196; idx += 256) {
            int i = idx / 14, j = idx % 14;
            s_tmp[idx] = 0.25f * (s_img[(2*i)*28 + 2*j]   + s_img[(2*i)*28 + 2*j + 1] +
                                  s_img[(2*i+1)*28 + 2*j] + s_img[(2*i+1)*28 + 2*j + 1]);
        }
        __syncthreads();
        if (br == 0) {
            for (int idx = tid; idx < 49; idx += 256) {
                int i = idx / 7, j = idx % 7;
                s_img[idx] = 0.25f * (s_tmp[(2*i)*14 + 2*j]   + s_tmp[(2*i)*14 + 2*j + 1] +
                                      s_tmp[(2*i+1)*14 + 2*j] + s_tmp[(2*i+1)*14 + 2*j + 1]);
            }
        } else {
            for (int idx = tid; idx < 196; idx += 256) s_img[idx] = s_tmp[idx];
        }
        __syncthreads();
    }
    if (br == 0)      conv_body<7, 7, 3, 5, 5>(c1w, c1b, yh1, yl1, partial_base, b, tid, s_img, s_w, s_red);
    else if (br == 1) conv_body<14, 14, 5, 10, 10>(c2w, c2b, yh2, yl2, partial_base + 65536, b, tid, s_img, s_w, s_red);
    else              conv_body<28, 28, 9, 20, 20>(c3w, c3b, yh3, yl3, partial_base + 131072, b, tid, s_img, s_w, s_red);
}

// ---------------- finalize BN from per-block partials ----------------
__global__ void bn_final_kernel(const float* __restrict__ partial_base, float* __restrict__ bnp_base) {
    int br = blockIdx.x;
    const float* pp = partial_base + br * 65536;
    float* bnp = bnp_base + br * 512;
    float N = (br == 0) ? 6400.f : ((br == 1) ? 25600.f : 102400.f);
    int c = threadIdx.x;  // 128
    float s = 0.f, q = 0.f;
    for (int blk = 0; blk < 256; ++blk) {
        s += pp[blk * 256 + c];
        q += pp[blk * 256 + 128 + c];
    }
    float mean = s / N;
    float var = q / N - mean * mean;
    float inv = rsqrtf(var + BN_EPS);
    bnp[256 + c] = inv;
    bnp[384 + c] = -mean * inv;
}

// ---------------- weight transform + bias fold + p3 zeroing (fused) ----------------
__global__ __launch_bounds__(256) void wtrans_zero_kernel(
        const float* __restrict__ w1, const float* __restrict__ w2,
        const float* __restrict__ w3, const float* __restrict__ bnp_base,
        const float* __restrict__ pb1, const float* __restrict__ pb2,
        const float* __restrict__ pb3,
        ushort_t* __restrict__ wh1, ushort_t* __restrict__ wl1,
        ushort_t* __restrict__ wh2, ushort_t* __restrict__ wl2,
        ushort_t* __restrict__ wh3, ushort_t* __restrict__ wl3,
        float* __restrict__ b1, float* __restrict__ b2, float* __restrict__ b3,
        float* __restrict__ p3zero) {
    __shared__ float tile[128 * 81];
    __shared__ float r2[2];
    int blk = blockIdx.x, tid = threadIdx.x;
    if (blk >= 768) {   // zero p3: 2304 blocks x 256 x float4 = 2,359,296 floats
        ((float4*)p3zero)[(blk - 768) * 256 + tid] = (float4){0.f, 0.f, 0.f, 0.f};
        return;
    }
    int br = blk >> 8, ch = blk & 255;
    const float* w; const float* pb; ushort_t* wh; ushort_t* wl; float* bf; int KK;
    if (br == 0)      { w = w1; pb = pb1; wh = wh1; wl = wl1; bf = b1; KK = 9;  }
    else if (br == 1) { w = w2; pb = pb2; wh = wh2; wl = wl2; bf = b2; KK = 25; }
    else              { w = w3; pb = pb3; wh = wh3; wl = wl3; bf = b3; KK = 81; }
    const float* bnp = bnp_base + br * 512;
    int n = 128 * KK;
    const float* wrow = w + ch * n;
    for (int i = tid; i < n; i += 256) tile[i] = wrow[i];   // coalesced fp32 read
    __syncthreads();
    for (int j = tid; j < n; j += 256) {                    // coalesced u16 writes (c innermost)
        int uv = j >> 7, c = j & 127;
        float val = tile[c * KK + uv] * bnp[256 + c];       // stride KK odd -> conflict-free
        unsigned short h = f2bf(val);
        unsigned short lo = f2bf(val - bf2f(h));
        int oidx = uv * 32768 + (ch << 7) + c;
        wh[oidx] = h; wl[oidx] = lo;
    }
    float s = 0.f;
    if (tid < 128) {
        for (int uv = 0; uv < KK; ++uv) s += tile[tid * KK + uv];
        s *= bnp[384 + tid];
    }
    for (int off = 32; off; off >>= 1) s += __shfl_down(s, off);
    if (tid < 128 && (tid & 63) == 0) r2[tid >> 6] = s;
    __syncthreads();
    if (tid == 0) bf[ch] = pb[ch] + r2[0] + r2[1];
}

// ================= split-bf16 MFMA GEMM body (device fn) =================
template<int S, int WO, int IHg, int IWg, int KS, int ZCH>
__device__ void gemm_body(const ushort_t* __restrict__ yh, const ushort_t* __restrict__ yl,
                          const ushort_t* __restrict__ wh, const ushort_t* __restrict__ wl,
                          float* __restrict__ p, int bx, int by, int bz, int tid,
                          ushort_t* Ash, ushort_t* Asl, ushort_t* Bsh, ushort_t* Bsl) {
    int bm = bx * 128, ch0 = by * 128;
    int arow = tid >> 2;
    int c0 = tid & 3;
    int sw0 = (c0 ^ ((arow >> 1) & 3)) * 8;
    int wA0 = arow * 32 + sw0;
    int wA1 = (arow + 64) * 32 + sw0;
    int m0 = bm + arow;
    int b0 = m0 / S, s0 = m0 % S;
    int abase0 = ((b0 * IHg + 2 * (s0 / WO)) * IWg + 2 * (s0 % WO)) * 128 + c0 * 8;
    int m1 = m0 + 64;
    int b1 = m1 / S, s1 = m1 % S;
    int abase1 = ((b1 * IHg + 2 * (s1 / WO)) * IWg + 2 * (s1 % WO)) * 128 + c0 * 8;
    int bbase0 = (ch0 + arow) * 128 + c0 * 8;
    int bbase1 = (ch0 + arow + 64) * 128 + c0 * 8;
    int lane = tid & 63, wid = tid >> 6;
    int wm = wid & 1, wn = wid >> 1;
    int quad = lane >> 4, l16 = lane & 15;
    int aoffL[4], boffL[4];
    #pragma unroll
    for (int mi = 0; mi < 4; ++mi) {
        int row = wm * 64 + mi * 16 + l16;
        aoffL[mi] = row * 32 + ((quad ^ ((row >> 1) & 3)) * 8);
    }
    #pragma unroll
    for (int ni = 0; ni < 4; ++ni) {
        int row = wn * 64 + ni * 16 + l16;
        boffL[ni] = row * 32 + ((quad ^ ((row >> 1) & 3)) * 8);
    }
    f32x4 acc[4][4];
    #pragma unroll
    for (int mi = 0; mi < 4; ++mi)
        #pragma unroll
        for (int ni = 0; ni < 4; ++ni)
            acc[mi][ni] = (f32x4){0.f, 0.f, 0.f, 0.f};

    int kc = bz * ZCH;
    int uv = kc >> 2, ci = kc & 3;
    int u = uv / KS, v = uv - u * KS;
    int aoff = (u * IWg + v) * 128 + (ci << 5);
    int boff = uv * 32768 + (ci << 5);
    int4 a0h = *reinterpret_cast<const int4*>(yh + abase0 + aoff);
    int4 a0l = *reinterpret_cast<const int4*>(yl + abase0 + aoff);
    int4 a1h = *reinterpret_cast<const int4*>(yh + abase1 + aoff);
    int4 a1l = *reinterpret_cast<const int4*>(yl + abase1 + aoff);
    int4 b0h = *reinterpret_cast<const int4*>(wh + bbase0 + boff);
    int4 b0l = *reinterpret_cast<const int4*>(wl + bbase0 + boff);
    int4 b1h = *reinterpret_cast<const int4*>(wh + bbase1 + boff);
    int4 b1l = *reinterpret_cast<const int4*>(wl + bbase1 + boff);

    for (int t = 0; t < ZCH; ++t) {
        __syncthreads();
        *reinterpret_cast<int4*>(&Ash[wA0]) = a0h;
        *reinterpret_cast<int4*>(&Asl[wA0]) = a0l;
        *reinterpret_cast<int4*>(&Ash[wA1]) = a1h;
        *reinterpret_cast<int4*>(&Asl[wA1]) = a1l;
        *reinterpret_cast<int4*>(&Bsh[wA0]) = b0h;
        *reinterpret_cast<int4*>(&Bsl[wA0]) = b0l;
        *reinterpret_cast<int4*>(&Bsh[wA1]) = b1h;
        *reinterpret_cast<int4*>(&Bsl[wA1]) = b1l;
        if (t + 1 < ZCH) {   // prefetch next chunk (uniform branch)
            ci = (ci + 1) & 3;
            if (ci == 0) { ++uv; ++v; if (v == KS) { v = 0; ++u; } }
            aoff = (u * IWg + v) * 128 + (ci << 5);
            boff = uv * 32768 + (ci << 5);
            a0h = *reinterpret_cast<const int4*>(yh + abase0 + aoff);
            a0l = *reinterpret_cast<const int4*>(yl + abase0 + aoff);
            a1h = *reinterpret_cast<const int4*>(yh + abase1 + aoff);
            a1l = *reinterpret_cast<const int4*>(yl + abase1 + aoff);
            b0h = *reinterpret_cast<const int4*>(wh + bbase0 + boff);
            b0l = *reinterpret_cast<const int4*>(wl + bbase0 + boff);
            b1h = *reinterpret_cast<const int4*>(wh + bbase1 + boff);
            b1l = *reinterpret_cast<const int4*>(wl + bbase1 + boff);
        }
        __syncthreads();
        short8 bh[4], bl[4];
        #pragma unroll
        for (int ni = 0; ni < 4; ++ni) {
            bh[ni] = *reinterpret_cast<const short8*>(&Bsh[boffL[ni]]);
            bl[ni] = *reinterpret_cast<const short8*>(&Bsl[boffL[ni]]);
        }
        #pragma unroll
        for (int mi = 0; mi < 4; ++mi) {
            short8 ah = *reinterpret_cast<const short8*>(&Ash[aoffL[mi]]);
            short8 al = *reinterpret_cast<const short8*>(&Asl[aoffL[mi]]);
            #pragma unroll
            for (int ni = 0; ni < 4; ++ni) {
                acc[mi][ni] = __builtin_amdgcn_mfma_f32_16x16x32_bf16(ah, bh[ni], acc[mi][ni], 0, 0, 0);
                acc[mi][ni] = __builtin_amdgcn_mfma_f32_16x16x32_bf16(al, bh[ni], acc[mi][ni], 0, 0, 0);
                acc[mi][ni] = __builtin_amdgcn_mfma_f32_16x16x32_bf16(ah, bl[ni], acc[mi][ni], 0, 0, 0);
            }
        }
    }
    // C/D layout (measured m89): col = lane&15, row = quad*4 + reg
    #pragma unroll
    for (int mi = 0; mi < 4; ++mi)
        #pragma unroll
        for (int ni = 0; ni < 4; ++ni) {
            int col = ch0 + wn * 64 + ni * 16 + l16;
            #pragma unroll
            for (int reg = 0; reg < 4; ++reg) {
                int row = bm + wm * 64 + mi * 16 + quad * 4 + reg;
                atomicAdd(p + (size_t)row * 256 + col, acc[mi][ni][reg]);
            }
        }
}

// gemm3: grid (72, 2, 6)
__global__ __launch_bounds__(256, 3) void gemm3_kernel(
        const ushort_t* __restrict__ yh, const ushort_t* __restrict__ yl,
        const ushort_t* __restrict__ wh, const ushort_t* __restrict__ wl,
        float* __restrict__ p) {
    __shared__ ushort_t Ash[128 * 32], Asl[128 * 32];
    __shared__ ushort_t Bsh[128 * 32], Bsl[128 * 32];
    gemm_body<36, 6, 20, 20, 9, 54>(yh, yl, wh, wl, p,
                                    blockIdx.x, blockIdx.y, blockIdx.z, threadIdx.x,
                                    Ash, Asl, Bsh, Bsl);
}

// gemm2 + gemm1 fused: blocks 0..359 = branch2 (18x2x10, ZCH=10); 360..503 = branch1 (8x2x9, ZCH=4)
__global__ __launch_bounds__(256, 3) void gemm21_kernel(
        const ushort_t* __restrict__ yh2, const ushort_t* __restrict__ yl2,
        const ushort_t* __restrict__ wh2, const ushort_t* __restrict__ wl2, float* __restrict__ p2,
        const ushort_t* __restrict__ yh1, const ushort_t* __restrict__ yl1,
        const ushort_t* __restrict__ wh1, const ushort_t* __restrict__ wl1, float* __restrict__ p1) {
    __shared__ ushort_t Ash[128 * 32], Asl[128 * 32];
    __shared__ ushort_t Bsh[128 * 32], Bsl[128 * 32];
    int blk = blockIdx.x, tid = threadIdx.x;
    if (blk < 360) {
        int z = blk / 36, rem = blk % 36, y = rem / 18, x = rem % 18;
        gemm_body<9, 3, 10, 10, 5, 10>(yh2, yl2, wh2, wl2, p2, x, y, z, tid, Ash, Asl, Bsh, Bsl);
    } else {
        int b = blk - 360;
        int z = b / 16, rem = b % 16, y = rem / 8, x = rem % 8;
        gemm_body<4, 2, 5, 5, 3, 4>(yh1, yl1, wh1, wl1, p1, x, y, z, tid, Ash, Asl, Bsh, Bsl);
    }
}

// ---------------- squash primary caps (all branches): p(B*S,256)+bias -> u(B,32*S,8) ----------------
__global__ void squash_all_kernel(const float* __restrict__ p1, const float* __restrict__ p2,
                                  const float* __restrict__ p3,
                                  const float* __restrict__ bias1, const float* __restrict__ bias2,
                                  const float* __restrict__ bias3,
                                  float* __restrict__ u1, float* __restrict__ u2,
                                  float* __restrict__ u3) {
    int blk = blockIdx.x;
    const float* p; const float* bias; float* u; int S;
    if (blk < 128)      { p = p1; bias = bias1; u = u1; S = 4; }
    else if (blk < 416) { p = p2; bias = bias2; u = u2; S = 9;  blk -= 128; }
    else                { p = p3; bias = bias3; u = u3; S = 36; blk -= 416; }
    int idx = blk * 256 + threadIdx.x;   // over 256*S*32, o innermost
    int o = idx & 31, rest = idx >> 5;
    int s = rest % S, b = rest / S;
    const float* pp = p + (size_t)(b * S + s) * 256 + o;
    float t[8]; float sn = 0.f;
    #pragma unroll
    for (int i = 0; i < 8; ++i) { t[i] = pp[i * 32] + bias[o + i * 32]; sn += t[i] * t[i]; }
    float f = sn / ((1.f + sn) * sqrtf(sn + SQ_EPS));
    float* up = u + (size_t)(b * (32 * S) + o * S + s) * 8;
    float4 w0 = {t[0] * f, t[1] * f, t[2] * f, t[3] * f};
    float4 w1 = {t[4] * f, t[5] * f, t[6] * f, t[7] * f};
    *reinterpret_cast<float4*>(up) = w0;
    *reinterpret_cast<float4*>(up + 4) = w1;
}

// ---------------- routing weights -> f32 transposed [n][g2][r][4] + zero p2/p1 ----------------
__global__ void rwtrans_zero_kernel(const float* __restrict__ w1, const float* __restrict__ w2,
                                    const float* __restrict__ w3,
                                    float* __restrict__ o1, float* __restrict__ o2,
                                    float* __restrict__ o3,
                                    float* __restrict__ p2, float* __restrict__ p1) {
    int blk = blockIdx.x;
    if (blk >= 7840) {   // zero p2 (576 blocks) then p1 (256 blocks)
        int zb = blk - 7840;
        if (zb < 576) ((float4*)p2)[zb * 256 + threadIdx.x] = (float4){0.f, 0.f, 0.f, 0.f};
        else          ((float4*)p1)[(zb - 576) * 256 + threadIdx.x] = (float4){0.f, 0.f, 0.f, 0.f};
        return;
    }
    int idx = blk * 256 + threadIdx.x;  // 7840*256 = 2,007,040 exact
    // dst flat = ((n*32+g2)*R + r)*4 + jj ; src = (n*R + r)*128 + g2*4 + jj
    if (idx < 163840) {           // br1: R=128
        int t = idx;
        int jj = t & 3; t >>= 2;
        int r = t & 127; t >>= 7;
        int g2 = t & 31; int n = t >> 5;
        o1[idx] = w1[(n * 128 + r) * 128 + g2 * 4 + jj];
    } else if (idx < 532480) {    // br2: R=288
        int t = idx - 163840;
        int jj = t & 3; t >>= 2;
        int r = t % 288; t /= 288;
        int g2 = t & 31; int n = t >> 5;
        o2[idx - 163840] = w2[(n * 288 + r) * 128 + g2 * 4 + jj];
    } else {                      // br3: R=1152
        int t = idx - 532480;
        int jj = t & 3; t >>= 2;
        int r = t % 1152; t /= 1152;
        int g2 = t & 31; int n = t >> 5;
        o3[idx - 532480] = w3[(n * 1152 + r) * 128 + g2 * 4 + jj];
    }
}

// ================= routing (3 iters), all branches fused =================
// v2: priors live in REGISTERS (bf16x2-packed, uint d[KMAX][8]) — no pri LDS at all.
// it0 sum accumulated in f32 during the build loop (free, and closer to f32 reference).
// Reductions: split-butterfly — 16-vector wave-sum in 15 shuffles (+2 full-wave steps),
// squash done by 16 lanes with a 4-step butterfly; 2 barriers/iteration.
template<int R>
__device__ void routing_body(const float* __restrict__ u, const float* __restrict__ rwt,
                             float* __restrict__ lens, int n, int b, int tid,
                             float* red, float* vsh, float* sred) {
    constexpr int KMAX = (R + 255) / 256;
    constexpr float invR = 1.0f / (float)R;
    int lane = tid & 63, wv = tid >> 6;

    unsigned int d[KMAX][8];   // priors, bf16x2 packed, per-thread rows r = tid + k*256
    float a[16];               // accumulator / reduction workspace
    float blog[KMAX];
    float v[16];

    #pragma unroll
    for (int o = 0; o < 16; ++o) a[o] = 0.f;
    #pragma unroll
    for (int k = 0; k < KMAX; ++k) blog[k] = 0.f;

    // ---- build priors into registers; accumulate it0 sums (f32) on the fly ----
    #pragma unroll
    for (int k = 0; k < KMAX; ++k) {
        int r = tid + k * 256;
        if (r < R) {
            const float4* up = (const float4*)(u + ((size_t)b * R + r) * 8);
            float4 ua = up[0], ub2 = up[1];
            float uu[8] = {ua.x, ua.y, ua.z, ua.w, ub2.x, ub2.y, ub2.z, ub2.w};
            float po[16];
            #pragma unroll
            for (int o = 0; o < 16; ++o) po[o] = 0.f;
            #pragma unroll
            for (int g2 = 0; g2 < 32; ++g2) {
                float4 w4 = *reinterpret_cast<const float4*>(rwt + (((size_t)n * 32 + g2) * R + r) * 4);
                float ui = uu[g2 >> 2];
                int o0 = (g2 & 3) * 4;
                po[o0 + 0] += ui * w4.x;
                po[o0 + 1] += ui * w4.y;
                po[o0 + 2] += ui * w4.z;
                po[o0 + 3] += ui * w4.w;
            }
            #pragma unroll
            for (int j = 0; j < 8; ++j)
                d[k][j] = (unsigned int)f2bf(po[2*j]) | ((unsigned int)f2bf(po[2*j+1]) << 16);
            #pragma unroll
            for (int o = 0; o < 16; ++o) a[o] += po[o];
        }
    }

    // ---- 3 v-updates: it=0 uniform coupling (1/R), it=1,2 softmax coupling ----
    for (int it = 0; it < 3; ++it) {
        if (it > 0) {
            float lsum = 0.f;
            #pragma unroll
            for (int o = 0; o < 16; ++o) a[o] = 0.f;
            #pragma unroll
            for (int k = 0; k < KMAX; ++k) {
                int r = tid + k * 256;
                if (r < R) {
                    float pv[16];
                    #pragma unroll
                    for (int j = 0; j < 8; ++j) {
                        pv[2*j]   = __uint_as_float(d[k][j] << 16);
                        pv[2*j+1] = __uint_as_float(d[k][j] & 0xffff0000u);
                    }
                    float dt0 = 0.f, dt1 = 0.f, dt2 = 0.f, dt3 = 0.f;
                    #pragma unroll
                    for (int o = 0; o < 4; ++o) {
                        dt0 += pv[o]      * v[o];
                        dt1 += pv[4 + o]  * v[4 + o];
                        dt2 += pv[8 + o]  * v[8 + o];
                        dt3 += pv[12 + o] * v[12 + o];
                    }
                    blog[k] += (dt0 + dt1) + (dt2 + dt3);
                    float e = __expf(blog[k]);
                    lsum += e;
                    #pragma unroll
                    for (int o = 0; o < 16; ++o) a[o] += e * pv[o];
                }
            }
            // wave-reduce lsum (full butterfly), one LDS word per wave
            lsum += __shfl_xor(lsum, 1);
            lsum += __shfl_xor(lsum, 2);
            lsum += __shfl_xor(lsum, 4);
            lsum += __shfl_xor(lsum, 8);
            lsum += __shfl_xor(lsum, 16);
            lsum += __shfl_xor(lsum, 32);
            if (lane == 0) sred[wv] = lsum;
        }
        // split-butterfly: 16-vector wave reduction in 15 shuffles.
        // invariant: after step k2, a[t] holds o = (t<<(k2+1)) | (lane & ((2<<k2)-1))
        #pragma unroll
        for (int k2 = 0; k2 < 4; ++k2) {
            int m = 1 << k2;
            int lb = (lane >> k2) & 1;
            #pragma unroll
            for (int t = 0; t < (8 >> k2); ++t) {
                float x0 = a[2 * t], x1 = a[2 * t + 1];
                float keep = lb ? x1 : x0;
                float send = lb ? x0 : x1;
                a[t] = keep + __shfl_xor(send, m);
            }
        }
        float tot = a[0];                 // per-wave sum for o = lane&15
        tot += __shfl_xor(tot, 16);
        tot += __shfl_xor(tot, 32);
        if (lane < 16) red[wv * 16 + lane] = tot;
        __syncthreads();
        if (tid < 16) {                   // lanes 0..15 of wave 0: combine + squash in parallel
            float vo = red[tid] + red[16 + tid] + red[32 + tid] + red[48 + tid];
            float scale = (it == 0) ? invR
                                    : 1.0f / (sred[0] + sred[1] + sred[2] + sred[3]);
            vo *= scale;
            float sn = vo * vo;
            sn += __shfl_xor(sn, 1);
            sn += __shfl_xor(sn, 2);
            sn += __shfl_xor(sn, 4);
            sn += __shfl_xor(sn, 8);
            float f = sn / ((1.f + sn) * sqrtf(sn + SQ_EPS));
            if (it == 2) {
                if (tid == 0) lens[b * 10 + n] = sqrtf(sn * f * f + SQ_EPS);
            } else {
                vsh[tid] = vo * f;
            }
        }
        __syncthreads();
        if (it < 2) {
            #pragma unroll
            for (int o = 0; o < 16; ++o) v[o] = vsh[o];   // same-address broadcast reads
        }
    }
}

__global__ __launch_bounds__(256, 4) void routing_all_kernel(
        const float* __restrict__ u1, const float* __restrict__ u2, const float* __restrict__ u3,
        const float* __restrict__ rwt1, const float* __restrict__ rwt2,
        const float* __restrict__ rwt3,
        float* __restrict__ l1, float* __restrict__ l2, float* __restrict__ l3) {
    __shared__ float red[64];
    __shared__ float vsh[16];
    __shared__ float sred[4];
    int n = blockIdx.x, b = blockIdx.y, br = 2 - blockIdx.z, tid = threadIdx.x;  // heavy branch first
    if (br == 0)      routing_body<128>(u1, rwt1, l1, n, b, tid, red, vsh, sred);
    else if (br == 1) routing_body<288>(u2, rwt2, l2, n, b, tid, red, vsh, sred);
    else              routing_body<1152>(u3, rwt3, l3, n, b, tid, red, vsh, sred);
}

// ---------------- final: softmax over classes of l1+l2+l3 ----------------
__global__ void final_softmax_kernel(const float* __restrict__ l1, const float* __restrict__ l2,
                                     const float* __restrict__ l3, float* __restrict__ out) {
    int b = threadIdx.x;
    float v[10]; float mx = -1e30f;
    #pragma unroll
    for (int n = 0; n < 10; ++n) {
        v[n] = l1[b * 10 + n] + l2[b * 10 + n] + l3[b * 10 + n];
        mx = fmaxf(mx, v[n]);
    }
    float s = 0.f;
    #pragma unroll
    for (int n = 0; n < 10; ++n) { v[n] = expf(v[n] - mx); s += v[n]; }
    float inv = 1.f / s;
    #pragma unroll
    for (int n = 0; n < 10; ++n) out[b * 10 + n] = v[n] * inv;
}

extern "C" void kernel_launch(void* const* d_in, const int* in_sizes, int n_in,
                              void* d_out, int out_size, void* d_ws, size_t ws_size,
                              hipStream_t stream) {
    const float* x   = (const float*)d_in[0];
    const float* c1w = (const float*)d_in[1];
    const float* c1b = (const float*)d_in[2];
    const float* p1w = (const float*)d_in[3];
    const float* p1b = (const float*)d_in[4];
    const float* d1w = (const float*)d_in[5];
    const float* c2w = (const float*)d_in[6];
    const float* c2b = (const float*)d_in[7];
    const float* p2w = (const float*)d_in[8];
    const float* p2b = (const float*)d_in[9];
    const float* d2w = (const float*)d_in[10];
    const float* c3w = (const float*)d_in[11];
    const float* c3b = (const float*)d_in[12];
    const float* p3w = (const float*)d_in[13];
    const float* p3b = (const float*)d_in[14];
    const float* d3w = (const float*)d_in[15];

    float* ws = (float*)d_ws;
    float* yh1f  = ws + 62720;      // 409600   [aliased by u1 later]
    float* yl1f  = ws + 472320;     // 409600
    float* yh2f  = ws + 881920;     // 1638400  [aliased by u2 later]
    float* yl2f  = ws + 2520320;    // 1638400
    float* yh3f  = ws + 4158720;    // 6553600  [aliased by u3 later]
    float* yl3f  = ws + 10712320;   // 6553600  [aliased by rwt after gemm3]
    float* wh1f  = ws + 17265920;   // 147456
    float* wl1f  = ws + 17413376;   // 147456
    float* wh2f  = ws + 17560832;   // 409600
    float* wl2f  = ws + 17970432;   // 409600
    float* wh3f  = ws + 18380032;   // 1327104  [aliased by p2 later]
    float* wl3f  = ws + 19707136;   // 1327104  [aliased by p1 later]
    float* p3    = ws + 21034240;   // 2359296  [bn partials scratch until zeroed]
    float* bnp1  = ws + 23393536;   // 512 x3
    float* bias1 = ws + 23395072;   // 256
    float* bias2 = ws + 23395328;   // 256
    float* bias3 = ws + 23395584;   // 256
    float* l1    = ws + 23395840;   // 2560
    float* l2    = ws + 23398400;   // 2560
    float* l3    = ws + 23400960;   // 2560

    ushort_t* yh1 = (ushort_t*)yh1f; ushort_t* yl1 = (ushort_t*)yl1f;
    ushort_t* yh2 = (ushort_t*)yh2f; ushort_t* yl2 = (ushort_t*)yl2f;
    ushort_t* yh3 = (ushort_t*)yh3f; ushort_t* yl3 = (ushort_t*)yl3f;
    ushort_t* wh1 = (ushort_t*)wh1f; ushort_t* wl1 = (ushort_t*)wl1f;
    ushort_t* wh2 = (ushort_t*)wh2f; ushort_t* wl2 = (ushort_t*)wl2f;
    ushort_t* wh3 = (ushort_t*)wh3f; ushort_t* wl3 = (ushort_t*)wl3f;
    float* u1 = yh1f;
    float* u2 = yh2f;
    float* u3 = yh3f;
    float* p2 = wh3f;
    float* p1 = wl3f;
    // f32 transposed routing weights in dead yl3 region (after gemm3):
    float* rwt1 = yl3f;                        // 163840 floats
    float* rwt2 = rwt1 + 163840;               // 368640
    float* rwt3 = rwt2 + 368640;               // 1474560 (total 2,007,040 <= 6,553,600)

    conv_all_kernel<<<768, 256, 0, stream>>>(x, c1w, c1b, c2w, c2b, c3w, c3b,
                                             yh1, yl1, yh2, yl2, yh3, yl3, p3);
    bn_final_kernel<<<3, 128, 0, stream>>>(p3, bnp1);
    wtrans_zero_kernel<<<3072, 256, 0, stream>>>(p1w, p2w, p3w, bnp1, p1b, p2b, p3b,
                                                 wh1, wl1, wh2, wl2, wh3, wl3,
                                                 bias1, bias2, bias3, p3);
    gemm3_kernel<<<dim3(72, 2, 6), 256, 0, stream>>>(yh3, yl3, wh3, wl3, p3);
    rwtrans_zero_kernel<<<8672, 256, 0, stream>>>(d1w, d2w, d3w, rwt1, rwt2, rwt3, p2, p1);
    gemm21_kernel<<<504, 256, 0, stream>>>(yh2, yl2, wh2, wl2, p2, yh1, yl1, wh1, wl1, p1);
    squash_all_kernel<<<1568, 256, 0, stream>>>(p1, p2, p3, bias1, bias2, bias3, u1, u2, u3);
    routing_all_kernel<<<dim3(10, 256, 3), 256, 0, stream>>>(u1, u2, u3, rwt1, rwt2, rwt3, l1, l2, l3);
    final_softmax_kernel<<<1, 256, 0, stream>>>(l1, l2, l3, (float*)d_out);
}

// Round 3
// 536.608 us; speedup vs baseline: 1.0248x; 1.0248x over previous
//
#include <hip/hip_runtime.h>
#include <math.h>

#define SQ_EPS 1e-12f
#define BN_EPS 1e-5f

typedef short short8 __attribute__((ext_vector_type(8)));
typedef float f32x4 __attribute__((ext_vector_type(4)));
typedef unsigned short ushort_t;

__device__ inline unsigned short f2bf(float x) {
    unsigned int u = __float_as_uint(x);
    unsigned int r = (u + 0x7fffu + ((u >> 16) & 1u)) >> 16;   // round-to-nearest-even
    return (unsigned short)r;
}
__device__ inline float bf2f(unsigned short h) {
    return __uint_as_float(((unsigned int)h) << 16);
}

// async global->LDS, 16B per lane; LDS dest = wave-uniform base + lane*16 (HW rule)
__device__ inline void gload_lds16(const ushort_t* g, ushort_t* l) {
    __builtin_amdgcn_global_load_lds(
        (const __attribute__((address_space(1))) void*)(g),
        (__attribute__((address_space(3))) void*)(l),
        16, 0, 0);
}

// ================= fused conv (3 branches, pooling inline) =================
template<int IH, int IW, int KS, int OH, int OW>
__device__ void conv_body(const float* __restrict__ w, const float* __restrict__ bias,
                          ushort_t* __restrict__ yh, ushort_t* __restrict__ yl,
                          float* __restrict__ partial,
                          int b, int tid, float* s_img, float* s_w, float* s_red) {
    constexpr int KK = KS * KS;
    constexpr int OS = OH * OW;
    for (int i = tid; i < 128 * KK; i += 256) s_w[i] = w[i];
    __syncthreads();
    int c = tid & 127, half = tid >> 7;
    float bias_c = bias[c];
    float bsum = 0.f, bsq = 0.f;
    for (int r = half; r < OH; r += 2) {
        float acc[OW];
        #pragma unroll
        for (int j = 0; j < OW; ++j) acc[j] = bias_c;
        for (int u = 0; u < KS; ++u) {
            float rg[OW + KS - 1];
            #pragma unroll
            for (int j = 0; j < OW + KS - 1; ++j) rg[j] = s_img[(r + u) * IW + j];
            #pragma unroll
            for (int v = 0; v < KS; ++v) {
                float wv = s_w[c * KK + u * KS + v];
                #pragma unroll
                for (int j = 0; j < OW; ++j) acc[j] += wv * rg[j + v];
            }
        }
        #pragma unroll
        for (int j = 0; j < OW; ++j) {
            float val = fmaxf(acc[j], 0.f);
            bsum += val; bsq += val * val;
            unsigned short h = f2bf(val);
            unsigned short lo = f2bf(val - bf2f(h));
            int oidx = ((b * OS) + r * OW + j) * 128 + c;
            yh[oidx] = h; yl[oidx] = lo;
        }
    }
    s_red[tid] = bsum; __syncthreads();
    if (tid < 128) partial[b * 256 + c] = s_red[tid] + s_red[tid + 128];
    __syncthreads();
    s_red[tid] = bsq; __syncthreads();
    if (tid < 128) partial[b * 256 + 128 + c] = s_red[tid] + s_red[tid + 128];
}

__global__ __launch_bounds__(256) void conv_all_kernel(
        const float* __restrict__ img,
        const float* __restrict__ c1w, const float* __restrict__ c1b,
        const float* __restrict__ c2w, const float* __restrict__ c2b,
        const float* __restrict__ c3w, const float* __restrict__ c3b,
        ushort_t* __restrict__ yh1, ushort_t* __restrict__ yl1,
        ushort_t* __restrict__ yh2, ushort_t* __restrict__ yl2,
        ushort_t* __restrict__ yh3, ushort_t* __restrict__ yl3,
        float* __restrict__ partial_base) {
    __shared__ float s_img[784];
    __shared__ float s_tmp[196];
    __shared__ float s_w[128 * 81];
    __shared__ float s_red[256];
    int br = blockIdx.x >> 8, b = blockIdx.x & 255, tid = threadIdx.x;
    const float* im = img + b * 784;
    for (int i = tid; i < 784; i += 256) s_img[i] = im[i];
    __syncthreads();
    if (br <= 1) {
        for (int idx = tid; idx < 196; idx += 256) {
            int i = idx / 14, j = idx % 14;
            s_tmp[idx] = 0.25f * (s_img[(2*i)*28 + 2*j]   + s_img[(2*i)*28 + 2*j + 1] +
                                  s_img[(2*i+1)*28 + 2*j] + s_img[(2*i+1)*28 + 2*j + 1]);
        }
        __syncthreads();
        if (br == 0) {
            for (int idx = tid; idx < 49; idx += 256) {
                int i = idx / 7, j = idx % 7;
                s_img[idx] = 0.25f * (s_tmp[(2*i)*14 + 2*j]   + s_tmp[(2*i)*14 + 2*j + 1] +
                                      s_tmp[(2*i+1)*14 + 2*j] + s_tmp[(2*i+1)*14 + 2*j + 1]);
            }
        } else {
            for (int idx = tid; idx < 196; idx += 256) s_img[idx] = s_tmp[idx];
        }
        __syncthreads();
    }
    if (br == 0)      conv_body<7, 7, 3, 5, 5>(c1w, c1b, yh1, yl1, partial_base, b, tid, s_img, s_w, s_red);
    else if (br == 1) conv_body<14, 14, 5, 10, 10>(c2w, c2b, yh2, yl2, partial_base + 65536, b, tid, s_img, s_w, s_red);
    else              conv_body<28, 28, 9, 20, 20>(c3w, c3b, yh3, yl3, partial_base + 131072, b, tid, s_img, s_w, s_red);
}

// ---------------- finalize BN from per-block partials ----------------
__global__ void bn_final_kernel(const float* __restrict__ partial_base, float* __restrict__ bnp_base) {
    int br = blockIdx.x;
    const float* pp = partial_base + br * 65536;
    float* bnp = bnp_base + br * 512;
    float N = (br == 0) ? 6400.f : ((br == 1) ? 25600.f : 102400.f);
    int c = threadIdx.x;  // 128
    float s = 0.f, q = 0.f;
    for (int blk = 0; blk < 256; ++blk) {
        s += pp[blk * 256 + c];
        q += pp[blk * 256 + 128 + c];
    }
    float mean = s / N;
    float var = q / N - mean * mean;
    float inv = rsqrtf(var + BN_EPS);
    bnp[256 + c] = inv;
    bnp[384 + c] = -mean * inv;
}

// ---------------- weight transform + bias fold + p3 zeroing (fused) ----------------
__global__ __launch_bounds__(256) void wtrans_zero_kernel(
        const float* __restrict__ w1, const float* __restrict__ w2,
        const float* __restrict__ w3, const float* __restrict__ bnp_base,
        const float* __restrict__ pb1, const float* __restrict__ pb2,
        const float* __restrict__ pb3,
        ushort_t* __restrict__ wh1, ushort_t* __restrict__ wl1,
        ushort_t* __restrict__ wh2, ushort_t* __restrict__ wl2,
        ushort_t* __restrict__ wh3, ushort_t* __restrict__ wl3,
        float* __restrict__ b1, float* __restrict__ b2, float* __restrict__ b3,
        float* __restrict__ p3zero) {
    __shared__ float tile[128 * 81];
    __shared__ float r2[2];
    int blk = blockIdx.x, tid = threadIdx.x;
    if (blk >= 768) {   // zero p3: 2304 blocks x 256 x float4 = 2,359,296 floats
        ((float4*)p3zero)[(blk - 768) * 256 + tid] = (float4){0.f, 0.f, 0.f, 0.f};
        return;
    }
    int br = blk >> 8, ch = blk & 255;
    const float* w; const float* pb; ushort_t* wh; ushort_t* wl; float* bf; int KK;
    if (br == 0)      { w = w1; pb = pb1; wh = wh1; wl = wl1; bf = b1; KK = 9;  }
    else if (br == 1) { w = w2; pb = pb2; wh = wh2; wl = wl2; bf = b2; KK = 25; }
    else              { w = w3; pb = pb3; wh = wh3; wl = wl3; bf = b3; KK = 81; }
    const float* bnp = bnp_base + br * 512;
    int n = 128 * KK;
    const float* wrow = w + ch * n;
    for (int i = tid; i < n; i += 256) tile[i] = wrow[i];   // coalesced fp32 read
    __syncthreads();
    for (int j = tid; j < n; j += 256) {                    // coalesced u16 writes (c innermost)
        int uv = j >> 7, c = j & 127;
        float val = tile[c * KK + uv] * bnp[256 + c];       // stride KK odd -> conflict-free
        unsigned short h = f2bf(val);
        unsigned short lo = f2bf(val - bf2f(h));
        int oidx = uv * 32768 + (ch << 7) + c;
        wh[oidx] = h; wl[oidx] = lo;
    }
    float s = 0.f;
    if (tid < 128) {
        for (int uv = 0; uv < KK; ++uv) s += tile[tid * KK + uv];
        s *= bnp[384 + tid];
    }
    for (int off = 32; off; off >>= 1) s += __shfl_down(s, off);
    if (tid < 128 && (tid & 63) == 0) r2[tid >> 6] = s;
    __syncthreads();
    if (tid == 0) bf[ch] = pb[ch] + r2[0] + r2[1];
}

// ================= split-bf16 MFMA GEMM body (device fn) =================
// v3: direct-to-LDS staging (global_load_lds), double-buffered (2x32KB),
// counted vmcnt(8) + raw s_barrier (no compiler vmcnt(0) drain).
// Read-side XOR swizzle preserved by inverse-swizzling the GLOBAL source column
// (c0s = c0 ^ s(arow), an involution) while LDS dest stays linear = base + lane*16.
template<int S, int WO, int IHg, int IWg, int KS, int ZCH>
__device__ void gemm_body(const ushort_t* __restrict__ yh, const ushort_t* __restrict__ yl,
                          const ushort_t* __restrict__ wh, const ushort_t* __restrict__ wl,
                          float* __restrict__ p, int bx, int by, int bz, int tid,
                          ushort_t* Ash, ushort_t* Asl, ushort_t* Bsh, ushort_t* Bsl) {
    int bm = bx * 128, ch0 = by * 128;
    int arow = tid >> 2;
    int c0 = tid & 3;
    int c0s = c0 ^ ((arow >> 1) & 3);       // inverse swizzle applied at the source
    int lane = tid & 63, wid = tid >> 6;
    int wb0 = wid * 512;                    // wave-uniform LDS staging base (rows wid*16..)
    int wb1 = 64 * 32 + wid * 512;          // rows 64+wid*16..
    int m0 = bm + arow;
    int b0 = m0 / S, s0 = m0 % S;
    int abase0 = ((b0 * IHg + 2 * (s0 / WO)) * IWg + 2 * (s0 % WO)) * 128 + c0s * 8;
    int m1 = m0 + 64;
    int b1 = m1 / S, s1 = m1 % S;
    int abase1 = ((b1 * IHg + 2 * (s1 / WO)) * IWg + 2 * (s1 % WO)) * 128 + c0s * 8;
    int bbase0 = (ch0 + arow) * 128 + c0s * 8;
    int bbase1 = (ch0 + arow + 64) * 128 + c0s * 8;
    int wm = (tid >> 6) & 1, wn = tid >> 7;
    int quad = lane >> 4, l16 = lane & 15;
    int aoffL[4], boffL[4];
    #pragma unroll
    for (int mi = 0; mi < 4; ++mi) {
        int row = wm * 64 + mi * 16 + l16;
        aoffL[mi] = row * 32 + ((quad ^ ((row >> 1) & 3)) * 8);
    }
    #pragma unroll
    for (int ni = 0; ni < 4; ++ni) {
        int row = wn * 64 + ni * 16 + l16;
        boffL[ni] = row * 32 + ((quad ^ ((row >> 1) & 3)) * 8);
    }
    f32x4 acc[4][4];
    #pragma unroll
    for (int mi = 0; mi < 4; ++mi)
        #pragma unroll
        for (int ni = 0; ni < 4; ++ni)
            acc[mi][ni] = (f32x4){0.f, 0.f, 0.f, 0.f};

    int kc = bz * ZCH;
    int uv = kc >> 2, ci = kc & 3;
    int u = uv / KS, v = uv - u * KS;
    int aoff = (u * IWg + v) * 128 + (ci << 5);
    int boff = uv * 32768 + (ci << 5);

    #define GEMM_ADV() do { ci = (ci + 1) & 3;                                   \
        if (ci == 0) { ++uv; ++v; if (v == KS) { v = 0; ++u; } }                 \
        aoff = (u * IWg + v) * 128 + (ci << 5);                                  \
        boff = uv * 32768 + (ci << 5); } while (0)
    #define GEMM_ISSUE(BSEL) do { int o_ = (BSEL) * 4096;                        \
        gload_lds16(yh + abase0 + aoff, Ash + o_ + wb0);                         \
        gload_lds16(yl + abase0 + aoff, Asl + o_ + wb0);                         \
        gload_lds16(yh + abase1 + aoff, Ash + o_ + wb1);                         \
        gload_lds16(yl + abase1 + aoff, Asl + o_ + wb1);                         \
        gload_lds16(wh + bbase0 + boff, Bsh + o_ + wb0);                         \
        gload_lds16(wl + bbase0 + boff, Bsl + o_ + wb0);                         \
        gload_lds16(wh + bbase1 + boff, Bsh + o_ + wb1);                         \
        gload_lds16(wl + bbase1 + boff, Bsl + o_ + wb1); } while (0)

    // prologue: chunks 0 and 1 in flight
    GEMM_ISSUE(0); GEMM_ADV();
    GEMM_ISSUE(1); GEMM_ADV();

    for (int t = 0; t < ZCH; ++t) {
        if (t < ZCH - 1) { asm volatile("s_waitcnt vmcnt(8)" ::: "memory"); }
        else             { asm volatile("s_waitcnt vmcnt(0)" ::: "memory"); }
        asm volatile("s_barrier" ::: "memory");     // chunk t resident in buf[t&1], no auto-drain
        int bo = (t & 1) * 4096;
        short8 bh[4], bl[4];
        #pragma unroll
        for (int ni = 0; ni < 4; ++ni) {
            bh[ni] = *reinterpret_cast<const short8*>(&Bsh[bo + boffL[ni]]);
            bl[ni] = *reinterpret_cast<const short8*>(&Bsl[bo + boffL[ni]]);
        }
        #pragma unroll
        for (int mi = 0; mi < 4; ++mi) {
            short8 ah = *reinterpret_cast<const short8*>(&Ash[bo + aoffL[mi]]);
            short8 al = *reinterpret_cast<const short8*>(&Asl[bo + aoffL[mi]]);
            #pragma unroll
            for (int ni = 0; ni < 4; ++ni) {
                acc[mi][ni] = __builtin_amdgcn_mfma_f32_16x16x32_bf16(ah, bh[ni], acc[mi][ni], 0, 0, 0);
                acc[mi][ni] = __builtin_amdgcn_mfma_f32_16x16x32_bf16(al, bh[ni], acc[mi][ni], 0, 0, 0);
                acc[mi][ni] = __builtin_amdgcn_mfma_f32_16x16x32_bf16(ah, bl[ni], acc[mi][ni], 0, 0, 0);
            }
        }
        asm volatile("s_barrier" ::: "memory");     // all waves done reading buf[t&1]
        if (t + 3 <= ZCH) {                         // overwrite buf[t&1] with chunk t+2
            GEMM_ISSUE(t & 1);
            GEMM_ADV();
        }
    }
    #undef GEMM_ISSUE
    #undef GEMM_ADV

    // C/D layout (measured m89): col = lane&15, row = quad*4 + reg
    #pragma unroll
    for (int mi = 0; mi < 4; ++mi)
        #pragma unroll
        for (int ni = 0; ni < 4; ++ni) {
            int col = ch0 + wn * 64 + ni * 16 + l16;
            #pragma unroll
            for (int reg = 0; reg < 4; ++reg) {
                int row = bm + wm * 64 + mi * 16 + quad * 4 + reg;
                atomicAdd(p + (size_t)row * 256 + col, acc[mi][ni][reg]);
            }
        }
}

// gemm3: grid (72, 2, 6) = 864 blocks, XCD-swizzled (864 % 8 == 0 -> bijective)
__global__ __launch_bounds__(256, 2) void gemm3_kernel(
        const ushort_t* __restrict__ yh, const ushort_t* __restrict__ yl,
        const ushort_t* __restrict__ wh, const ushort_t* __restrict__ wl,
        float* __restrict__ p) {
    __shared__ ushort_t Ash[2 * 4096], Asl[2 * 4096];
    __shared__ ushort_t Bsh[2 * 4096], Bsl[2 * 4096];
    int bid = blockIdx.x + 72 * (blockIdx.y + 2 * blockIdx.z);
    int swz = (bid & 7) * 108 + (bid >> 3);       // contiguous x-chunks per XCD (B-panel reuse)
    int x = swz % 72, r = swz / 72;
    gemm_body<36, 6, 20, 20, 9, 54>(yh, yl, wh, wl, p,
                                    x, r & 1, r >> 1, threadIdx.x,
                                    Ash, Asl, Bsh, Bsl);
}

// gemm2 + gemm1 fused: 504 blocks XCD-swizzled; swz 0..359 = branch2, 360..503 = branch1
__global__ __launch_bounds__(256, 2) void gemm21_kernel(
        const ushort_t* __restrict__ yh2, const ushort_t* __restrict__ yl2,
        const ushort_t* __restrict__ wh2, const ushort_t* __restrict__ wl2, float* __restrict__ p2,
        const ushort_t* __restrict__ yh1, const ushort_t* __restrict__ yl1,
        const ushort_t* __restrict__ wh1, const ushort_t* __restrict__ wl1, float* __restrict__ p1) {
    __shared__ ushort_t Ash[2 * 4096], Asl[2 * 4096];
    __shared__ ushort_t Bsh[2 * 4096], Bsl[2 * 4096];
    int bid = blockIdx.x;
    int swz = (bid & 7) * 63 + (bid >> 3);        // 504 % 8 == 0 -> bijective
    int tid = threadIdx.x;
    if (swz < 360) {
        int z = swz / 36, rem = swz % 36, y = rem / 18, x = rem % 18;
        gemm_body<9, 3, 10, 10, 5, 10>(yh2, yl2, wh2, wl2, p2, x, y, z, tid, Ash, Asl, Bsh, Bsl);
    } else {
        int b = swz - 360;
        int z = b / 16, rem = b % 16, y = rem / 8, x = rem % 8;
        gemm_body<4, 2, 5, 5, 3, 4>(yh1, yl1, wh1, wl1, p1, x, y, z, tid, Ash, Asl, Bsh, Bsl);
    }
}

// ---------------- squash primary caps (all branches): p(B*S,256)+bias -> u(B,32*S,8) ----------------
__global__ void squash_all_kernel(const float* __restrict__ p1, const float* __restrict__ p2,
                                  const float* __restrict__ p3,
                                  const float* __restrict__ bias1, const float* __restrict__ bias2,
                                  const float* __restrict__ bias3,
                                  float* __restrict__ u1, float* __restrict__ u2,
                                  float* __restrict__ u3) {
    int blk = blockIdx.x;
    const float* p; const float* bias; float* u; int S;
    if (blk < 128)      { p = p1; bias = bias1; u = u1; S = 4; }
    else if (blk < 416) { p = p2; bias = bias2; u = u2; S = 9;  blk -= 128; }
    else                { p = p3; bias = bias3; u = u3; S = 36; blk -= 416; }
    int idx = blk * 256 + threadIdx.x;   // over 256*S*32, o innermost
    int o = idx & 31, rest = idx >> 5;
    int s = rest % S, b = rest / S;
    const float* pp = p + (size_t)(b * S + s) * 256 + o;
    float t[8]; float sn = 0.f;
    #pragma unroll
    for (int i = 0; i < 8; ++i) { t[i] = pp[i * 32] + bias[o + i * 32]; sn += t[i] * t[i]; }
    float f = sn / ((1.f + sn) * sqrtf(sn + SQ_EPS));
    float* up = u + (size_t)(b * (32 * S) + o * S + s) * 8;
    float4 w0 = {t[0] * f, t[1] * f, t[2] * f, t[3] * f};
    float4 w1 = {t[4] * f, t[5] * f, t[6] * f, t[7] * f};
    *reinterpret_cast<float4*>(up) = w0;
    *reinterpret_cast<float4*>(up + 4) = w1;
}

// ---------------- routing weights -> f32 transposed [n][g2][r][4] + zero p2/p1 ----------------
__global__ void rwtrans_zero_kernel(const float* __restrict__ w1, const float* __restrict__ w2,
                                    const float* __restrict__ w3,
                                    float* __restrict__ o1, float* __restrict__ o2,
                                    float* __restrict__ o3,
                                    float* __restrict__ p2, float* __restrict__ p1) {
    int blk = blockIdx.x;
    if (blk >= 7840) {   // zero p2 (576 blocks) then p1 (256 blocks)
        int zb = blk - 7840;
        if (zb < 576) ((float4*)p2)[zb * 256 + threadIdx.x] = (float4){0.f, 0.f, 0.f, 0.f};
        else          ((float4*)p1)[(zb - 576) * 256 + threadIdx.x] = (float4){0.f, 0.f, 0.f, 0.f};
        return;
    }
    int idx = blk * 256 + threadIdx.x;  // 7840*256 = 2,007,040 exact
    // dst flat = ((n*32+g2)*R + r)*4 + jj ; src = (n*R + r)*128 + g2*4 + jj
    if (idx < 163840) {           // br1: R=128
        int t = idx;
        int jj = t & 3; t >>= 2;
        int r = t & 127; t >>= 7;
        int g2 = t & 31; int n = t >> 5;
        o1[idx] = w1[(n * 128 + r) * 128 + g2 * 4 + jj];
    } else if (idx < 532480) {    // br2: R=288
        int t = idx - 163840;
        int jj = t & 3; t >>= 2;
        int r = t % 288; t /= 288;
        int g2 = t & 31; int n = t >> 5;
        o2[idx - 163840] = w2[(n * 288 + r) * 128 + g2 * 4 + jj];
    } else {                      // br3: R=1152
        int t = idx - 532480;
        int jj = t & 3; t >>= 2;
        int r = t % 1152; t /= 1152;
        int g2 = t & 31; int n = t >> 5;
        o3[idx - 532480] = w3[(n * 1152 + r) * 128 + g2 * 4 + jj];
    }
}

// ================= routing (3 iters), all branches fused =================
// priors live in REGISTERS (bf16x2-packed); it0 sum folded into build;
// split-butterfly reductions; 2 barriers/iteration.
template<int R>
__device__ void routing_body(const float* __restrict__ u, const float* __restrict__ rwt,
                             float* __restrict__ lens, int n, int b, int tid,
                             float* red, float* vsh, float* sred) {
    constexpr int KMAX = (R + 255) / 256;
    constexpr float invR = 1.0f / (float)R;
    int lane = tid & 63, wv = tid >> 6;

    unsigned int d[KMAX][8];   // priors, bf16x2 packed, per-thread rows r = tid + k*256
    float a[16];               // accumulator / reduction workspace
    float blog[KMAX];
    float v[16];

    #pragma unroll
    for (int o = 0; o < 16; ++o) a[o] = 0.f;
    #pragma unroll
    for (int k = 0; k < KMAX; ++k) blog[k] = 0.f;

    // ---- build priors into registers; accumulate it0 sums (f32) on the fly ----
    #pragma unroll
    for (int k = 0; k < KMAX; ++k) {
        int r = tid + k * 256;
        if (r < R) {
            const float4* up = (const float4*)(u + ((size_t)b * R + r) * 8);
            float4 ua = up[0], ub2 = up[1];
            float uu[8] = {ua.x, ua.y, ua.z, ua.w, ub2.x, ub2.y, ub2.z, ub2.w};
            float po[16];
            #pragma unroll
            for (int o = 0; o < 16; ++o) po[o] = 0.f;
            #pragma unroll
            for (int g2 = 0; g2 < 32; ++g2) {
                float4 w4 = *reinterpret_cast<const float4*>(rwt + (((size_t)n * 32 + g2) * R + r) * 4);
                float ui = uu[g2 >> 2];
                int o0 = (g2 & 3) * 4;
                po[o0 + 0] += ui * w4.x;
                po[o0 + 1] += ui * w4.y;
                po[o0 + 2] += ui * w4.z;
                po[o0 + 3] += ui * w4.w;
            }
            #pragma unroll
            for (int j = 0; j < 8; ++j)
                d[k][j] = (unsigned int)f2bf(po[2*j]) | ((unsigned int)f2bf(po[2*j+1]) << 16);
            #pragma unroll
            for (int o = 0; o < 16; ++o) a[o] += po[o];
        }
    }

    // ---- 3 v-updates: it=0 uniform coupling (1/R), it=1,2 softmax coupling ----
    for (int it = 0; it < 3; ++it) {
        if (it > 0) {
            float lsum = 0.f;
            #pragma unroll
            for (int o = 0; o < 16; ++o) a[o] = 0.f;
            #pragma unroll
            for (int k = 0; k < KMAX; ++k) {
                int r = tid + k * 256;
                if (r < R) {
                    float pv[16];
                    #pragma unroll
                    for (int j = 0; j < 8; ++j) {
                        pv[2*j]   = __uint_as_float(d[k][j] << 16);
                        pv[2*j+1] = __uint_as_float(d[k][j] & 0xffff0000u);
                    }
                    float dt0 = 0.f, dt1 = 0.f, dt2 = 0.f, dt3 = 0.f;
                    #pragma unroll
                    for (int o = 0; o < 4; ++o) {
                        dt0 += pv[o]      * v[o];
                        dt1 += pv[4 + o]  * v[4 + o];
                        dt2 += pv[8 + o]  * v[8 + o];
                        dt3 += pv[12 + o] * v[12 + o];
                    }
                    blog[k] += (dt0 + dt1) + (dt2 + dt3);
                    float e = __expf(blog[k]);
                    lsum += e;
                    #pragma unroll
                    for (int o = 0; o < 16; ++o) a[o] += e * pv[o];
                }
            }
            // wave-reduce lsum (full butterfly), one LDS word per wave
            lsum += __shfl_xor(lsum, 1);
            lsum += __shfl_xor(lsum, 2);
            lsum += __shfl_xor(lsum, 4);
            lsum += __shfl_xor(lsum, 8);
            lsum += __shfl_xor(lsum, 16);
            lsum += __shfl_xor(lsum, 32);
            if (lane == 0) sred[wv] = lsum;
        }
        // split-butterfly: 16-vector wave reduction in 15 shuffles.
        #pragma unroll
        for (int k2 = 0; k2 < 4; ++k2) {
            int m = 1 << k2;
            int lb = (lane >> k2) & 1;
            #pragma unroll
            for (int t = 0; t < (8 >> k2); ++t) {
                float x0 = a[2 * t], x1 = a[2 * t + 1];
                float keep = lb ? x1 : x0;
                float send = lb ? x0 : x1;
                a[t] = keep + __shfl_xor(send, m);
            }
        }
        float tot = a[0];                 // per-wave sum for o = lane&15
        tot += __shfl_xor(tot, 16);
        tot += __shfl_xor(tot, 32);
        if (lane < 16) red[wv * 16 + lane] = tot;
        __syncthreads();
        if (tid < 16) {                   // lanes 0..15 of wave 0: combine + squash in parallel
            float vo = red[tid] + red[16 + tid] + red[32 + tid] + red[48 + tid];
            float scale = (it == 0) ? invR
                                    : 1.0f / (sred[0] + sred[1] + sred[2] + sred[3]);
            vo *= scale;
            float sn = vo * vo;
            sn += __shfl_xor(sn, 1);
            sn += __shfl_xor(sn, 2);
            sn += __shfl_xor(sn, 4);
            sn += __shfl_xor(sn, 8);
            float f = sn / ((1.f + sn) * sqrtf(sn + SQ_EPS));
            if (it == 2) {
                if (tid == 0) lens[b * 10 + n] = sqrtf(sn * f * f + SQ_EPS);
            } else {
                vsh[tid] = vo * f;
            }
        }
        __syncthreads();
        if (it < 2) {
            #pragma unroll
            for (int o = 0; o < 16; ++o) v[o] = vsh[o];   // same-address broadcast reads
        }
    }
}

__global__ __launch_bounds__(256, 4) void routing_all_kernel(
        const float* __restrict__ u1, const float* __restrict__ u2, const float* __restrict__ u3,
        const float* __restrict__ rwt1, const float* __restrict__ rwt2,
        const float* __restrict__ rwt3,
        float* __restrict__ l1, float* __restrict__ l2, float* __restrict__ l3) {
    __shared__ float red[64];
    __shared__ float vsh[16];
    __shared__ float sred[4];
    int n = blockIdx.x, b = blockIdx.y, br = 2 - blockIdx.z, tid = threadIdx.x;  // heavy branch first
    if (br == 0)      routing_body<128>(u1, rwt1, l1, n, b, tid, red, vsh, sred);
    else if (br == 1) routing_body<288>(u2, rwt2, l2, n, b, tid, red, vsh, sred);
    else              routing_body<1152>(u3, rwt3, l3, n, b, tid, red, vsh, sred);
}

// ---------------- final: softmax over classes of l1+l2+l3 ----------------
__global__ void final_softmax_kernel(const float* __restrict__ l1, const float* __restrict__ l2,
                                     const float* __restrict__ l3, float* __restrict__ out) {
    int b = threadIdx.x;
    float v[10]; float mx = -1e30f;
    #pragma unroll
    for (int n = 0; n < 10; ++n) {
        v[n] = l1[b * 10 + n] + l2[b * 10 + n] + l3[b * 10 + n];
        mx = fmaxf(mx, v[n]);
    }
    float s = 0.f;
    #pragma unroll
    for (int n = 0; n < 10; ++n) { v[n] = expf(v[n] - mx); s += v[n]; }
    float inv = 1.f / s;
    #pragma unroll
    for (int n = 0; n < 10; ++n) out[b * 10 + n] = v[n] * inv;
}

extern "C" void kernel_launch(void* const* d_in, const int* in_sizes, int n_in,
                              void* d_out, int out_size, void* d_ws, size_t ws_size,
                              hipStream_t stream) {
    const float* x   = (const float*)d_in[0];
    const float* c1w = (const float*)d_in[1];
    const float* c1b = (const float*)d_in[2];
    const float* p1w = (const float*)d_in[3];
    const float* p1b = (const float*)d_in[4];
    const float* d1w = (const float*)d_in[5];
    const float* c2w = (const float*)d_in[6];
    const float* c2b = (const float*)d_in[7];
    const float* p2w = (const float*)d_in[8];
    const float* p2b = (const float*)d_in[9];
    const float* d2w = (const float*)d_in[10];
    const float* c3w = (const float*)d_in[11];
    const float* c3b = (const float*)d_in[12];
    const float* p3w = (const float*)d_in[13];
    const float* p3b = (const float*)d_in[14];
    const float* d3w = (const float*)d_in[15];

    float* ws = (float*)d_ws;
    float* yh1f  = ws + 62720;      // 409600   [aliased by u1 later]
    float* yl1f  = ws + 472320;     // 409600
    float* yh2f  = ws + 881920;     // 1638400  [aliased by u2 later]
    float* yl2f  = ws + 2520320;    // 1638400
    float* yh3f  = ws + 4158720;    // 6553600  [aliased by u3 later]
    float* yl3f  = ws + 10712320;   // 6553600  [aliased by rwt after gemm3]
    float* wh1f  = ws + 17265920;   // 147456
    float* wl1f  = ws + 17413376;   // 147456
    float* wh2f  = ws + 17560832;   // 409600
    float* wl2f  = ws + 17970432;   // 409600
    float* wh3f  = ws + 18380032;   // 1327104  [aliased by p2 later]
    float* wl3f  = ws + 19707136;   // 1327104  [aliased by p1 later]
    float* p3    = ws + 21034240;   // 2359296  [bn partials scratch until zeroed]
    float* bnp1  = ws + 23393536;   // 512 x3
    float* bias1 = ws + 23395072;   // 256
    float* bias2 = ws + 23395328;   // 256
    float* bias3 = ws + 23395584;   // 256
    float* l1    = ws + 23395840;   // 2560
    float* l2    = ws + 23398400;   // 2560
    float* l3    = ws + 23400960;   // 2560

    ushort_t* yh1 = (ushort_t*)yh1f; ushort_t* yl1 = (ushort_t*)yl1f;
    ushort_t* yh2 = (ushort_t*)yh2f; ushort_t* yl2 = (ushort_t*)yl2f;
    ushort_t* yh3 = (ushort_t*)yh3f; ushort_t* yl3 = (ushort_t*)yl3f;
    ushort_t* wh1 = (ushort_t*)wh1f; ushort_t* wl1 = (ushort_t*)wl1f;
    ushort_t* wh2 = (ushort_t*)wh2f; ushort_t* wl2 = (ushort_t*)wl2f;
    ushort_t* wh3 = (ushort_t*)wh3f; ushort_t* wl3 = (ushort_t*)wl3f;
    float* u1 = yh1f;
    float* u2 = yh2f;
    float* u3 = yh3f;
    float* p2 = wh3f;
    float* p1 = wl3f;
    // f32 transposed routing weights in dead yl3 region (after gemm3):
    float* rwt1 = yl3f;                        // 163840 floats
    float* rwt2 = rwt1 + 163840;               // 368640
    float* rwt3 = rwt2 + 368640;               // 1474560 (total 2,007,040 <= 6,553,600)

    conv_all_kernel<<<768, 256, 0, stream>>>(x, c1w, c1b, c2w, c2b, c3w, c3b,
                                             yh1, yl1, yh2, yl2, yh3, yl3, p3);
    bn_final_kernel<<<3, 128, 0, stream>>>(p3, bnp1);
    wtrans_zero_kernel<<<3072, 256, 0, stream>>>(p1w, p2w, p3w, bnp1, p1b, p2b, p3b,
                                                 wh1, wl1, wh2, wl2, wh3, wl3,
                                                 bias1, bias2, bias3, p3);
    gemm3_kernel<<<dim3(72, 2, 6), 256, 0, stream>>>(yh3, yl3, wh3, wl3, p3);
    rwtrans_zero_kernel<<<8672, 256, 0, stream>>>(d1w, d2w, d3w, rwt1, rwt2, rwt3, p2, p1);
    gemm21_kernel<<<504, 256, 0, stream>>>(yh2, yl2, wh2, wl2, p2, yh1, yl1, wh1, wl1, p1);
    squash_all_kernel<<<1568, 256, 0, stream>>>(p1, p2, p3, bias1, bias2, bias3, u1, u2, u3);
    routing_all_kernel<<<dim3(10, 256, 3), 256, 0, stream>>>(u1, u2, u3, rwt1, rwt2, rwt3, l1, l2, l3);
    final_softmax_kernel<<<1, 256, 0, stream>>>(l1, l2, l3, (float*)d_out);
}

// Round 6
// 494.688 us; speedup vs baseline: 1.1117x; 1.0847x over previous
//
#include <hip/hip_runtime.h>
#include <math.h>

#define SQ_EPS 1e-12f
#define BN_EPS 1e-5f

typedef short short8 __attribute__((ext_vector_type(8)));
typedef float f32x4 __attribute__((ext_vector_type(4)));
typedef unsigned short ushort_t;

__device__ inline unsigned short f2bf(float x) {
    unsigned int u = __float_as_uint(x);
    unsigned int r = (u + 0x7fffu + ((u >> 16) & 1u)) >> 16;   // round-to-nearest-even
    return (unsigned short)r;
}
__device__ inline float bf2f(unsigned short h) {
    return __uint_as_float(((unsigned int)h) << 16);
}

// async global->LDS, 16B per lane; LDS dest = wave-uniform base + lane*16 (HW rule)
__device__ inline void gload_lds16(const ushort_t* g, ushort_t* l) {
    __builtin_amdgcn_global_load_lds(
        (const __attribute__((address_space(1))) void*)(g),
        (__attribute__((address_space(3))) void*)(l),
        16, 0, 0);
}

// ================= fused conv (3 branches, pooling inline) =================
template<int IH, int IW, int KS, int OH, int OW>
__device__ void conv_body(const float* __restrict__ w, const float* __restrict__ bias,
                          ushort_t* __restrict__ yh, ushort_t* __restrict__ yl,
                          float* __restrict__ partial,
                          int b, int tid, float* s_img, float* s_w, float* s_red) {
    constexpr int KK = KS * KS;
    constexpr int OS = OH * OW;
    for (int i = tid; i < 128 * KK; i += 256) s_w[i] = w[i];
    __syncthreads();
    int c = tid & 127, half = tid >> 7;
    float bias_c = bias[c];
    float bsum = 0.f, bsq = 0.f;
    for (int r = half; r < OH; r += 2) {
        float acc[OW];
        #pragma unroll
        for (int j = 0; j < OW; ++j) acc[j] = bias_c;
        for (int u = 0; u < KS; ++u) {
            float rg[OW + KS - 1];
            #pragma unroll
            for (int j = 0; j < OW + KS - 1; ++j) rg[j] = s_img[(r + u) * IW + j];
            #pragma unroll
            for (int v = 0; v < KS; ++v) {
                float wv = s_w[c * KK + u * KS + v];
                #pragma unroll
                for (int j = 0; j < OW; ++j) acc[j] += wv * rg[j + v];
            }
        }
        #pragma unroll
        for (int j = 0; j < OW; ++j) {
            float val = fmaxf(acc[j], 0.f);
            bsum += val; bsq += val * val;
            unsigned short h = f2bf(val);
            unsigned short lo = f2bf(val - bf2f(h));
            int oidx = ((b * OS) + r * OW + j) * 128 + c;
            yh[oidx] = h; yl[oidx] = lo;
        }
    }
    s_red[tid] = bsum; __syncthreads();
    if (tid < 128) partial[b * 256 + c] = s_red[tid] + s_red[tid + 128];
    __syncthreads();
    s_red[tid] = bsq; __syncthreads();
    if (tid < 128) partial[b * 256 + 128 + c] = s_red[tid] + s_red[tid + 128];
}

__global__ __launch_bounds__(256) void conv_all_kernel(
        const float* __restrict__ img,
        const float* __restrict__ c1w, const float* __restrict__ c1b,
        const float* __restrict__ c2w, const float* __restrict__ c2b,
        const float* __restrict__ c3w, const float* __restrict__ c3b,
        ushort_t* __restrict__ yh1, ushort_t* __restrict__ yl1,
        ushort_t* __restrict__ yh2, ushort_t* __restrict__ yl2,
        ushort_t* __restrict__ yh3, ushort_t* __restrict__ yl3,
        float* __restrict__ partial_base) {
    __shared__ float s_img[784];
    __shared__ float s_tmp[196];
    __shared__ float s_w[128 * 81];
    __shared__ float s_red[256];
    int br = blockIdx.x >> 8, b = blockIdx.x & 255, tid = threadIdx.x;
    const float* im = img + b * 784;
    for (int i = tid; i < 784; i += 256) s_img[i] = im[i];
    __syncthreads();
    if (br <= 1) {
        for (int idx = tid; idx < 196; idx += 256) {
            int i = idx / 14, j = idx % 14;
            s_tmp[idx] = 0.25f * (s_img[(2*i)*28 + 2*j]   + s_img[(2*i)*28 + 2*j + 1] +
                                  s_img[(2*i+1)*28 + 2*j] + s_img[(2*i+1)*28 + 2*j + 1]);
        }
        __syncthreads();
        if (br == 0) {
            for (int idx = tid; idx < 49; idx += 256) {
                int i = idx / 7, j = idx % 7;
                s_img[idx] = 0.25f * (s_tmp[(2*i)*14 + 2*j]   + s_tmp[(2*i)*14 + 2*j + 1] +
                                      s_tmp[(2*i+1)*14 + 2*j] + s_tmp[(2*i+1)*14 + 2*j + 1]);
            }
        } else {
            for (int idx = tid; idx < 196; idx += 256) s_img[idx] = s_tmp[idx];
        }
        __syncthreads();
    }
    if (br == 0)      conv_body<7, 7, 3, 5, 5>(c1w, c1b, yh1, yl1, partial_base, b, tid, s_img, s_w, s_red);
    else if (br == 1) conv_body<14, 14, 5, 10, 10>(c2w, c2b, yh2, yl2, partial_base + 65536, b, tid, s_img, s_w, s_red);
    else              conv_body<28, 28, 9, 20, 20>(c3w, c3b, yh3, yl3, partial_base + 131072, b, tid, s_img, s_w, s_red);
}

// ---------------- finalize BN from per-block partials ----------------
__global__ void bn_final_kernel(const float* __restrict__ partial_base, float* __restrict__ bnp_base) {
    int br = blockIdx.x;
    const float* pp = partial_base + br * 65536;
    float* bnp = bnp_base + br * 512;
    float N = (br == 0) ? 6400.f : ((br == 1) ? 25600.f : 102400.f);
    int c = threadIdx.x;  // 128
    float s = 0.f, q = 0.f;
    for (int blk = 0; blk < 256; ++blk) {
        s += pp[blk * 256 + c];
        q += pp[blk * 256 + 128 + c];
    }
    float mean = s / N;
    float var = q / N - mean * mean;
    float inv = rsqrtf(var + BN_EPS);
    bnp[256 + c] = inv;
    bnp[384 + c] = -mean * inv;
}

// ---------------- weight transform + bias fold + p3 zeroing (fused) ----------------
__global__ __launch_bounds__(256) void wtrans_zero_kernel(
        const float* __restrict__ w1, const float* __restrict__ w2,
        const float* __restrict__ w3, const float* __restrict__ bnp_base,
        const float* __restrict__ pb1, const float* __restrict__ pb2,
        const float* __restrict__ pb3,
        ushort_t* __restrict__ wh1, ushort_t* __restrict__ wl1,
        ushort_t* __restrict__ wh2, ushort_t* __restrict__ wl2,
        ushort_t* __restrict__ wh3, ushort_t* __restrict__ wl3,
        float* __restrict__ b1, float* __restrict__ b2, float* __restrict__ b3,
        float* __restrict__ p3zero) {
    __shared__ float tile[128 * 81];
    __shared__ float r2[2];
    int blk = blockIdx.x, tid = threadIdx.x;
    if (blk >= 768) {   // zero p3: 2304 blocks x 256 x float4 = 2,359,296 floats
        ((float4*)p3zero)[(blk - 768) * 256 + tid] = (float4){0.f, 0.f, 0.f, 0.f};
        return;
    }
    int br = blk >> 8, ch = blk & 255;
    const float* w; const float* pb; ushort_t* wh; ushort_t* wl; float* bf; int KK;
    if (br == 0)      { w = w1; pb = pb1; wh = wh1; wl = wl1; bf = b1; KK = 9;  }
    else if (br == 1) { w = w2; pb = pb2; wh = wh2; wl = wl2; bf = b2; KK = 25; }
    else              { w = w3; pb = pb3; wh = wh3; wl = wl3; bf = b3; KK = 81; }
    const float* bnp = bnp_base + br * 512;
    int n = 128 * KK;
    const float* wrow = w + ch * n;
    for (int i = tid; i < n; i += 256) tile[i] = wrow[i];   // coalesced fp32 read
    __syncthreads();
    for (int j = tid; j < n; j += 256) {                    // coalesced u16 writes (c innermost)
        int uv = j >> 7, c = j & 127;
        float val = tile[c * KK + uv] * bnp[256 + c];       // stride KK odd -> conflict-free
        unsigned short h = f2bf(val);
        unsigned short lo = f2bf(val - bf2f(h));
        int oidx = uv * 32768 + (ch << 7) + c;
        wh[oidx] = h; wl[oidx] = lo;
    }
    float s = 0.f;
    if (tid < 128) {
        for (int uv = 0; uv < KK; ++uv) s += tile[tid * KK + uv];
        s *= bnp[384 + tid];
    }
    for (int off = 32; off; off >>= 1) s += __shfl_down(s, off);
    if (tid < 128 && (tid & 63) == 0) r2[tid >> 6] = s;
    __syncthreads();
    if (tid == 0) bf[ch] = pb[ch] + r2[0] + r2[1];
}

// ================= split-bf16 MFMA GEMM body (device fn) =================
// direct-to-LDS staging (global_load_lds), double-buffered (2x32KB),
// counted vmcnt(8) + raw s_barrier. Read-side XOR swizzle preserved by
// inverse-swizzling the GLOBAL source column (involution) with linear LDS dest.
template<int S, int WO, int IHg, int IWg, int KS, int ZCH>
__device__ void gemm_body(const ushort_t* __restrict__ yh, const ushort_t* __restrict__ yl,
                          const ushort_t* __restrict__ wh, const ushort_t* __restrict__ wl,
                          float* __restrict__ p, int bx, int by, int bz, int tid,
                          ushort_t* Ash, ushort_t* Asl, ushort_t* Bsh, ushort_t* Bsl) {
    int bm = bx * 128, ch0 = by * 128;
    int arow = tid >> 2;
    int c0 = tid & 3;
    int c0s = c0 ^ ((arow >> 1) & 3);       // inverse swizzle applied at the source
    int lane = tid & 63, wid = tid >> 6;
    int wb0 = wid * 512;                    // wave-uniform LDS staging base (rows wid*16..)
    int wb1 = 64 * 32 + wid * 512;          // rows 64+wid*16..
    int m0 = bm + arow;
    int b0 = m0 / S, s0 = m0 % S;
    int abase0 = ((b0 * IHg + 2 * (s0 / WO)) * IWg + 2 * (s0 % WO)) * 128 + c0s * 8;
    int m1 = m0 + 64;
    int b1 = m1 / S, s1 = m1 % S;
    int abase1 = ((b1 * IHg + 2 * (s1 / WO)) * IWg + 2 * (s1 % WO)) * 128 + c0s * 8;
    int bbase0 = (ch0 + arow) * 128 + c0s * 8;
    int bbase1 = (ch0 + arow + 64) * 128 + c0s * 8;
    int wm = (tid >> 6) & 1, wn = tid >> 7;
    int quad = lane >> 4, l16 = lane & 15;
    int aoffL[4], boffL[4];
    #pragma unroll
    for (int mi = 0; mi < 4; ++mi) {
        int row = wm * 64 + mi * 16 + l16;
        aoffL[mi] = row * 32 + ((quad ^ ((row >> 1) & 3)) * 8);
    }
    #pragma unroll
    for (int ni = 0; ni < 4; ++ni) {
        int row = wn * 64 + ni * 16 + l16;
        boffL[ni] = row * 32 + ((quad ^ ((row >> 1) & 3)) * 8);
    }
    f32x4 acc[4][4];
    #pragma unroll
    for (int mi = 0; mi < 4; ++mi)
        #pragma unroll
        for (int ni = 0; ni < 4; ++ni)
            acc[mi][ni] = (f32x4){0.f, 0.f, 0.f, 0.f};

    int kc = bz * ZCH;
    int uv = kc >> 2, ci = kc & 3;
    int u = uv / KS, v = uv - u * KS;
    int aoff = (u * IWg + v) * 128 + (ci << 5);
    int boff = uv * 32768 + (ci << 5);

    #define GEMM_ADV() do { ci = (ci + 1) & 3;                                   \
        if (ci == 0) { ++uv; ++v; if (v == KS) { v = 0; ++u; } }                 \
        aoff = (u * IWg + v) * 128 + (ci << 5);                                  \
        boff = uv * 32768 + (ci << 5); } while (0)
    #define GEMM_ISSUE(BSEL) do { int o_ = (BSEL) * 4096;                        \
        gload_lds16(yh + abase0 + aoff, Ash + o_ + wb0);                         \
        gload_lds16(yl + abase0 + aoff, Asl + o_ + wb0);                         \
        gload_lds16(yh + abase1 + aoff, Ash + o_ + wb1);                         \
        gload_lds16(yl + abase1 + aoff, Asl + o_ + wb1);                         \
        gload_lds16(wh + bbase0 + boff, Bsh + o_ + wb0);                         \
        gload_lds16(wl + bbase0 + boff, Bsl + o_ + wb0);                         \
        gload_lds16(wh + bbase1 + boff, Bsh + o_ + wb1);                         \
        gload_lds16(wl + bbase1 + boff, Bsl + o_ + wb1); } while (0)

    // prologue: chunks 0 and 1 in flight
    GEMM_ISSUE(0); GEMM_ADV();
    GEMM_ISSUE(1); GEMM_ADV();

    for (int t = 0; t < ZCH; ++t) {
        if (t < ZCH - 1) { asm volatile("s_waitcnt vmcnt(8)" ::: "memory"); }
        else             { asm volatile("s_waitcnt vmcnt(0)" ::: "memory"); }
        asm volatile("s_barrier" ::: "memory");     // chunk t resident in buf[t&1]
        int bo = (t & 1) * 4096;
        short8 bh[4], bl[4];
        #pragma unroll
        for (int ni = 0; ni < 4; ++ni) {
            bh[ni] = *reinterpret_cast<const short8*>(&Bsh[bo + boffL[ni]]);
            bl[ni] = *reinterpret_cast<const short8*>(&Bsl[bo + boffL[ni]]);
        }
        #pragma unroll
        for (int mi = 0; mi < 4; ++mi) {
            short8 ah = *reinterpret_cast<const short8*>(&Ash[bo + aoffL[mi]]);
            short8 al = *reinterpret_cast<const short8*>(&Asl[bo + aoffL[mi]]);
            #pragma unroll
            for (int ni = 0; ni < 4; ++ni) {
                acc[mi][ni] = __builtin_amdgcn_mfma_f32_16x16x32_bf16(ah, bh[ni], acc[mi][ni], 0, 0, 0);
                acc[mi][ni] = __builtin_amdgcn_mfma_f32_16x16x32_bf16(al, bh[ni], acc[mi][ni], 0, 0, 0);
                acc[mi][ni] = __builtin_amdgcn_mfma_f32_16x16x32_bf16(ah, bl[ni], acc[mi][ni], 0, 0, 0);
            }
        }
        asm volatile("s_barrier" ::: "memory");     // all waves done reading buf[t&1]
        if (t + 3 <= ZCH) {                         // overwrite buf[t&1] with chunk t+2
            GEMM_ISSUE(t & 1);
            GEMM_ADV();
        }
    }
    #undef GEMM_ISSUE
    #undef GEMM_ADV

    // C/D layout (measured m89): col = lane&15, row = quad*4 + reg
    #pragma unroll
    for (int mi = 0; mi < 4; ++mi)
        #pragma unroll
        for (int ni = 0; ni < 4; ++ni) {
            int col = ch0 + wn * 64 + ni * 16 + l16;
            #pragma unroll
            for (int reg = 0; reg < 4; ++reg) {
                int row = bm + wm * 64 + mi * 16 + quad * 4 + reg;
                atomicAdd(p + (size_t)row * 256 + col, acc[mi][ni][reg]);
            }
        }
}

// gemm3: grid (72, 2, 6) = 864 blocks, XCD-swizzled (864 % 8 == 0 -> bijective)
__global__ __launch_bounds__(256, 2) void gemm3_kernel(
        const ushort_t* __restrict__ yh, const ushort_t* __restrict__ yl,
        const ushort_t* __restrict__ wh, const ushort_t* __restrict__ wl,
        float* __restrict__ p) {
    __shared__ ushort_t Ash[2 * 4096], Asl[2 * 4096];
    __shared__ ushort_t Bsh[2 * 4096], Bsl[2 * 4096];
    int bid = blockIdx.x + 72 * (blockIdx.y + 2 * blockIdx.z);
    int swz = (bid & 7) * 108 + (bid >> 3);       // contiguous x-chunks per XCD (B-panel reuse)
    int x = swz % 72, r = swz / 72;
    gemm_body<36, 6, 20, 20, 9, 54>(yh, yl, wh, wl, p,
                                    x, r & 1, r >> 1, threadIdx.x,
                                    Ash, Asl, Bsh, Bsl);
}

// gemm2 + gemm1 fused: 504 blocks XCD-swizzled; swz 0..359 = branch2, 360..503 = branch1
__global__ __launch_bounds__(256, 2) void gemm21_kernel(
        const ushort_t* __restrict__ yh2, const ushort_t* __restrict__ yl2,
        const ushort_t* __restrict__ wh2, const ushort_t* __restrict__ wl2, float* __restrict__ p2,
        const ushort_t* __restrict__ yh1, const ushort_t* __restrict__ yl1,
        const ushort_t* __restrict__ wh1, const ushort_t* __restrict__ wl1, float* __restrict__ p1) {
    __shared__ ushort_t Ash[2 * 4096], Asl[2 * 4096];
    __shared__ ushort_t Bsh[2 * 4096], Bsl[2 * 4096];
    int bid = blockIdx.x;
    int swz = (bid & 7) * 63 + (bid >> 3);        // 504 % 8 == 0 -> bijective
    int tid = threadIdx.x;
    if (swz < 360) {
        int z = swz / 36, rem = swz % 36, y = rem / 18, x = rem % 18;
        gemm_body<9, 3, 10, 10, 5, 10>(yh2, yl2, wh2, wl2, p2, x, y, z, tid, Ash, Asl, Bsh, Bsl);
    } else {
        int b = swz - 360;
        int z = b / 16, rem = b % 16, y = rem / 8, x = rem % 8;
        gemm_body<4, 2, 5, 5, 3, 4>(yh1, yl1, wh1, wl1, p1, x, y, z, tid, Ash, Asl, Bsh, Bsl);
    }
}

// ---------------- squash primary caps (all branches): p(B*S,256)+bias -> u(B,32*S,8) ----------------
__global__ void squash_all_kernel(const float* __restrict__ p1, const float* __restrict__ p2,
                                  const float* __restrict__ p3,
                                  const float* __restrict__ bias1, const float* __restrict__ bias2,
                                  const float* __restrict__ bias3,
                                  float* __restrict__ u1, float* __restrict__ u2,
                                  float* __restrict__ u3) {
    int blk = blockIdx.x;
    const float* p; const float* bias; float* u; int S;
    if (blk < 128)      { p = p1; bias = bias1; u = u1; S = 4; }
    else if (blk < 416) { p = p2; bias = bias2; u = u2; S = 9;  blk -= 128; }
    else                { p = p3; bias = bias3; u = u3; S = 36; blk -= 416; }
    int idx = blk * 256 + threadIdx.x;   // over 256*S*32, o innermost
    int o = idx & 31, rest = idx >> 5;
    int s = rest % S, b = rest / S;
    const float* pp = p + (size_t)(b * S + s) * 256 + o;
    float t[8]; float sn = 0.f;
    #pragma unroll
    for (int i = 0; i < 8; ++i) { t[i] = pp[i * 32] + bias[o + i * 32]; sn += t[i] * t[i]; }
    float f = sn / ((1.f + sn) * sqrtf(sn + SQ_EPS));
    float* up = u + (size_t)(b * (32 * S) + o * S + s) * 8;
    float4 w0 = {t[0] * f, t[1] * f, t[2] * f, t[3] * f};
    float4 w1 = {t[4] * f, t[5] * f, t[6] * f, t[7] * f};
    *reinterpret_cast<float4*>(up) = w0;
    *reinterpret_cast<float4*>(up + 4) = w1;
}

// ---------------- routing weights -> f32 transposed [n][g2][r][4] + zero p2/p1 ----------------
__global__ void rwtrans_zero_kernel(const float* __restrict__ w1, const float* __restrict__ w2,
                                    const float* __restrict__ w3,
                                    float* __restrict__ o1, float* __restrict__ o2,
                                    float* __restrict__ o3,
                                    float* __restrict__ p2, float* __restrict__ p1) {
    int blk = blockIdx.x;
    if (blk >= 7840) {   // zero p2 (576 blocks) then p1 (256 blocks)
        int zb = blk - 7840;
        if (zb < 576) ((float4*)p2)[zb * 256 + threadIdx.x] = (float4){0.f, 0.f, 0.f, 0.f};
        else          ((float4*)p1)[(zb - 576) * 256 + threadIdx.x] = (float4){0.f, 0.f, 0.f, 0.f};
        return;
    }
    int idx = blk * 256 + threadIdx.x;  // 7840*256 = 2,007,040 exact
    // dst flat = ((n*32+g2)*R + r)*4 + jj ; src = (n*R + r)*128 + g2*4 + jj
    if (idx < 163840) {           // br1: R=128
        int t = idx;
        int jj = t & 3; t >>= 2;
        int r = t & 127; t >>= 7;
        int g2 = t & 31; int n = t >> 5;
        o1[idx] = w1[(n * 128 + r) * 128 + g2 * 4 + jj];
    } else if (idx < 532480) {    // br2: R=288
        int t = idx - 163840;
        int jj = t & 3; t >>= 2;
        int r = t % 288; t /= 288;
        int g2 = t & 31; int n = t >> 5;
        o2[idx - 163840] = w2[(n * 288 + r) * 128 + g2 * 4 + jj];
    } else {                      // br3: R=1152
        int t = idx - 532480;
        int jj = t & 3; t >>= 2;
        int r = t % 1152; t /= 1152;
        int g2 = t & 31; int n = t >> 5;
        o3[idx - 532480] = w3[(n * 1152 + r) * 128 + g2 * 4 + jj];
    }
}

// ================= routing (3 iters), all branches fused =================
// v2 structure (priors in registers, bf16x2-packed) with the ONE fix that matters:
// __launch_bounds__(256, 2) lifts the 64-VGPR cap -> d[KMAX][8] stays in registers
// (Round-3 profile showed 120 MB of scratch spill at the (256,4) cap).
template<int R>
__device__ void routing_body(const float* __restrict__ u, const float* __restrict__ rwt,
                             float* __restrict__ lens, int n, int b, int tid,
                             float* red, float* vsh, float* sred) {
    constexpr int KMAX = (R + 255) / 256;
    constexpr float invR = 1.0f / (float)R;
    int lane = tid & 63, wv = tid >> 6;

    unsigned int d[KMAX][8];   // priors, bf16x2 packed, per-thread rows r = tid + k*256
    float a[16];               // accumulator / reduction workspace
    float blog[KMAX];
    float v[16];

    #pragma unroll
    for (int o = 0; o < 16; ++o) a[o] = 0.f;
    #pragma unroll
    for (int k = 0; k < KMAX; ++k) blog[k] = 0.f;

    // ---- build priors into registers; accumulate it0 sums (f32) on the fly ----
    #pragma unroll
    for (int k = 0; k < KMAX; ++k) {
        int r = tid + k * 256;
        if (r < R) {
            const float4* up = (const float4*)(u + ((size_t)b * R + r) * 8);
            float4 ua = up[0], ub2 = up[1];
            float uu[8] = {ua.x, ua.y, ua.z, ua.w, ub2.x, ub2.y, ub2.z, ub2.w};
            float po[16];
            #pragma unroll
            for (int o = 0; o < 16; ++o) po[o] = 0.f;
            #pragma unroll
            for (int g2 = 0; g2 < 32; ++g2) {
                float4 w4 = *reinterpret_cast<const float4*>(rwt + (((size_t)n * 32 + g2) * R + r) * 4);
                float ui = uu[g2 >> 2];
                int o0 = (g2 & 3) * 4;
                po[o0 + 0] += ui * w4.x;
                po[o0 + 1] += ui * w4.y;
                po[o0 + 2] += ui * w4.z;
                po[o0 + 3] += ui * w4.w;
            }
            #pragma unroll
            for (int j = 0; j < 8; ++j)
                d[k][j] = (unsigned int)f2bf(po[2*j]) | ((unsigned int)f2bf(po[2*j+1]) << 16);
            #pragma unroll
            for (int o = 0; o < 16; ++o) a[o] += po[o];
        }
    }

    // ---- 3 v-updates: it=0 uniform coupling (1/R), it=1,2 softmax coupling ----
    for (int it = 0; it < 3; ++it) {
        if (it > 0) {
            float lsum = 0.f;
            #pragma unroll
            for (int o = 0; o < 16; ++o) a[o] = 0.f;
            #pragma unroll
            for (int k = 0; k < KMAX; ++k) {
                int r = tid + k * 256;
                if (r < R) {
                    float pv[16];
                    #pragma unroll
                    for (int j = 0; j < 8; ++j) {
                        pv[2*j]   = __uint_as_float(d[k][j] << 16);
                        pv[2*j+1] = __uint_as_float(d[k][j] & 0xffff0000u);
                    }
                    float dt0 = 0.f, dt1 = 0.f, dt2 = 0.f, dt3 = 0.f;
                    #pragma unroll
                    for (int o = 0; o < 4; ++o) {
                        dt0 += pv[o]      * v[o];
                        dt1 += pv[4 + o]  * v[4 + o];
                        dt2 += pv[8 + o]  * v[8 + o];
                        dt3 += pv[12 + o] * v[12 + o];
                    }
                    blog[k] += (dt0 + dt1) + (dt2 + dt3);
                    float e = __expf(blog[k]);
                    lsum += e;
                    #pragma unroll
                    for (int o = 0; o < 16; ++o) a[o] += e * pv[o];
                }
            }
            // wave-reduce lsum (full butterfly), one LDS word per wave
            lsum += __shfl_xor(lsum, 1);
            lsum += __shfl_xor(lsum, 2);
            lsum += __shfl_xor(lsum, 4);
            lsum += __shfl_xor(lsum, 8);
            lsum += __shfl_xor(lsum, 16);
            lsum += __shfl_xor(lsum, 32);
            if (lane == 0) sred[wv] = lsum;
        }
        // split-butterfly: 16-vector wave reduction in 15 shuffles.
        #pragma unroll
        for (int k2 = 0; k2 < 4; ++k2) {
            int m = 1 << k2;
            int lb = (lane >> k2) & 1;
            #pragma unroll
            for (int t = 0; t < (8 >> k2); ++t) {
                float x0 = a[2 * t], x1 = a[2 * t + 1];
                float keep = lb ? x1 : x0;
                float send = lb ? x0 : x1;
                a[t] = keep + __shfl_xor(send, m);
            }
        }
        float tot = a[0];                 // per-wave sum for o = lane&15
        tot += __shfl_xor(tot, 16);
        tot += __shfl_xor(tot, 32);
        if (lane < 16) red[wv * 16 + lane] = tot;
        __syncthreads();
        if (tid < 16) {                   // lanes 0..15 of wave 0: combine + squash in parallel
            float vo = red[tid] + red[16 + tid] + red[32 + tid] + red[48 + tid];
            float scale = (it == 0) ? invR
                                    : 1.0f / (sred[0] + sred[1] + sred[2] + sred[3]);
            vo *= scale;
            float sn = vo * vo;
            sn += __shfl_xor(sn, 1);
            sn += __shfl_xor(sn, 2);
            sn += __shfl_xor(sn, 4);
            sn += __shfl_xor(sn, 8);
            float f = sn / ((1.f + sn) * sqrtf(sn + SQ_EPS));
            if (it == 2) {
                if (tid == 0) lens[b * 10 + n] = sqrtf(sn * f * f + SQ_EPS);
            } else {
                vsh[tid] = vo * f;
            }
        }
        __syncthreads();
        if (it < 2) {
            #pragma unroll
            for (int o = 0; o < 16; ++o) v[o] = vsh[o];   // same-address broadcast reads
        }
    }
}

__global__ __launch_bounds__(256, 2) void routing_all_kernel(
        const float* __restrict__ u1, const float* __restrict__ u2, const float* __restrict__ u3,
        const float* __restrict__ rwt1, const float* __restrict__ rwt2,
        const float* __restrict__ rwt3,
        float* __restrict__ l1, float* __restrict__ l2, float* __restrict__ l3) {
    __shared__ float red[64];
    __shared__ float vsh[16];
    __shared__ float sred[4];
    int n = blockIdx.x, b = blockIdx.y, br = 2 - blockIdx.z, tid = threadIdx.x;  // heavy branch first
    if (br == 0)      routing_body<128>(u1, rwt1, l1, n, b, tid, red, vsh, sred);
    else if (br == 1) routing_body<288>(u2, rwt2, l2, n, b, tid, red, vsh, sred);
    else              routing_body<1152>(u3, rwt3, l3, n, b, tid, red, vsh, sred);
}

// ---------------- final: softmax over classes of l1+l2+l3 ----------------
__global__ void final_softmax_kernel(const float* __restrict__ l1, const float* __restrict__ l2,
                                     const float* __restrict__ l3, float* __restrict__ out) {
    int b = threadIdx.x;
    float v[10]; float mx = -1e30f;
    #pragma unroll
    for (int n = 0; n < 10; ++n) {
        v[n] = l1[b * 10 + n] + l2[b * 10 + n] + l3[b * 10 + n];
        mx = fmaxf(mx, v[n]);
    }
    float s = 0.f;
    #pragma unroll
    for (int n = 0; n < 10; ++n) { v[n] = expf(v[n] - mx); s += v[n]; }
    float inv = 1.f / s;
    #pragma unroll
    for (int n = 0; n < 10; ++n) out[b * 10 + n] = v[n] * inv;
}

extern "C" void kernel_launch(void* const* d_in, const int* in_sizes, int n_in,
                              void* d_out, int out_size, void* d_ws, size_t ws_size,
                              hipStream_t stream) {
    const float* x   = (const float*)d_in[0];
    const float* c1w = (const float*)d_in[1];
    const float* c1b = (const float*)d_in[2];
    const float* p1w = (const float*)d_in[3];
    const float* p1b = (const float*)d_in[4];
    const float* d1w = (const float*)d_in[5];
    const float* c2w = (const float*)d_in[6];
    const float* c2b = (const float*)d_in[7];
    const float* p2w = (const float*)d_in[8];
    const float* p2b = (const float*)d_in[9];
    const float* d2w = (const float*)d_in[10];
    const float* c3w = (const float*)d_in[11];
    const float* c3b = (const float*)d_in[12];
    const float* p3w = (const float*)d_in[13];
    const float* p3b = (const float*)d_in[14];
    const float* d3w = (const float*)d_in[15];

    float* ws = (float*)d_ws;
    float* yh1f  = ws + 62720;      // 409600   [aliased by u1 later]
    float* yl1f  = ws + 472320;     // 409600
    float* yh2f  = ws + 881920;     // 1638400  [aliased by u2 later]
    float* yl2f  = ws + 2520320;    // 1638400
    float* yh3f  = ws + 4158720;    // 6553600  [aliased by u3 later]
    float* yl3f  = ws + 10712320;   // 6553600  [aliased by rwt after gemm3]
    float* wh1f  = ws + 17265920;   // 147456
    float* wl1f  = ws + 17413376;   // 147456
    float* wh2f  = ws + 17560832;   // 409600
    float* wl2f  = ws + 17970432;   // 409600
    float* wh3f  = ws + 18380032;   // 1327104  [aliased by p2 later]
    float* wl3f  = ws + 19707136;   // 1327104  [aliased by p1 later]
    float* p3    = ws + 21034240;   // 2359296  [bn partials scratch until zeroed]
    float* bnp1  = ws + 23393536;   // 512 x3
    float* bias1 = ws + 23395072;   // 256
    float* bias2 = ws + 23395328;   // 256
    float* bias3 = ws + 23395584;   // 256
    float* l1    = ws + 23395840;   // 2560
    float* l2    = ws + 23398400;   // 2560
    float* l3    = ws + 23400960;   // 2560

    ushort_t* yh1 = (ushort_t*)yh1f; ushort_t* yl1 = (ushort_t*)yl1f;
    ushort_t* yh2 = (ushort_t*)yh2f; ushort_t* yl2 = (ushort_t*)yl2f;
    ushort_t* yh3 = (ushort_t*)yh3f; ushort_t* yl3 = (ushort_t*)yl3f;
    ushort_t* wh1 = (ushort_t*)wh1f; ushort_t* wl1 = (ushort_t*)wl1f;
    ushort_t* wh2 = (ushort_t*)wh2f; ushort_t* wl2 = (ushort_t*)wl2f;
    ushort_t* wh3 = (ushort_t*)wh3f; ushort_t* wl3 = (ushort_t*)wl3f;
    float* u1 = yh1f;
    float* u2 = yh2f;
    float* u3 = yh3f;
    float* p2 = wh3f;
    float* p1 = wl3f;
    // f32 transposed routing weights in dead yl3 region (after gemm3):
    float* rwt1 = yl3f;                        // 163840 floats
    float* rwt2 = rwt1 + 163840;               // 368640
    float* rwt3 = rwt2 + 368640;               // 1474560 (total 2,007,040 <= 6,553,600)

    conv_all_kernel<<<768, 256, 0, stream>>>(x, c1w, c1b, c2w, c2b, c3w, c3b,
                                             yh1, yl1, yh2, yl2, yh3, yl3, p3);
    bn_final_kernel<<<3, 128, 0, stream>>>(p3, bnp1);
    wtrans_zero_kernel<<<3072, 256, 0, stream>>>(p1w, p2w, p3w, bnp1, p1b, p2b, p3b,
                                                 wh1, wl1, wh2, wl2, wh3, wl3,
                                                 bias1, bias2, bias3, p3);
    gemm3_kernel<<<dim3(72, 2, 6), 256, 0, stream>>>(yh3, yl3, wh3, wl3, p3);
    rwtrans_zero_kernel<<<8672, 256, 0, stream>>>(d1w, d2w, d3w, rwt1, rwt2, rwt3, p2, p1);
    gemm21_kernel<<<504, 256, 0, stream>>>(yh2, yl2, wh2, wl2, p2, yh1, yl1, wh1, wl1, p1);
    squash_all_kernel<<<1568, 256, 0, stream>>>(p1, p2, p3, bias1, bias2, bias3, u1, u2, u3);
    routing_all_kernel<<<dim3(10, 256, 3), 256, 0, stream>>>(u1, u2, u3, rwt1, rwt2, rwt3, l1, l2, l3);
    final_softmax_kernel<<<1, 256, 0, stream>>>(l1, l2, l3, (float*)d_out);
}